// Round 1
// baseline (2527.856 us; speedup 1.0000x reference)
//
#include <hip/hip_runtime.h>
#include <stdint.h>

#define NB  2
#define NC  128
#define NT  32768
#define KFB 512
#define NUP 2048
#define CAP 14336

typedef unsigned int u32;

__device__ __forceinline__ u32 f2key(float v){
  u32 u = __float_as_uint(v);
  return (u & 0x80000000u) ? ~u : (u | 0x80000000u);
}
__device__ __forceinline__ float key2f(u32 k){
  u32 u = (k & 0x80000000u) ? (k & 0x7FFFFFFFu) : ~k;
  return __uint_as_float(u);
}

// ============ K0: init (zero histograms + counters) ============
__global__ void k_init(u32* __restrict__ h1, u32* __restrict__ h2, int* __restrict__ counts){
  int i = blockIdx.x*256 + threadIdx.x;   // grid 16 -> 4096 threads
  if (i < 2048) h1[i] = 0u;
  else if (i < 4096) h2[i-2048] = 0u;
  if (i < NB) counts[i] = 0;
}

// ============ K1: filterbank analysis ============
// spec[b,c,t] = sum_{k<512} x[b, t+k-256] * fb[c,k]   (zero-pad x)
__global__ __launch_bounds__(256) void k_fb(const float* __restrict__ x,
                                            const float* __restrict__ fb,
                                            float* __restrict__ spec){
  const int t0 = blockIdx.x * 128;
  const int c0 = blockIdx.y * 64;
  const int b  = blockIdx.z;
  __shared__ float win[640];
  __shared__ float fbl[32][64];
  const int tid = threadIdx.x;
  for (int j = tid; j < 640; j += 256){
    int t = t0 - 256 + j;
    win[j] = (t >= 0 && t < NT) ? x[b*NT + t] : 0.0f;
  }
  const int cg = tid & 7;
  const int tl = (tid >> 3) * 4;
  float acc[8][4];
  #pragma unroll
  for (int i=0;i<8;++i){
    #pragma unroll
    for (int j=0;j<4;++j) acc[i][j]=0.0f;
  }
  for (int k0 = 0; k0 < KFB; k0 += 32){
    __syncthreads();
    #pragma unroll
    for (int r = 0; r < 8; ++r){
      int flat = r*256 + tid;
      int kk = flat >> 6, c = flat & 63;
      fbl[kk][c] = fb[(c0+c)*KFB + k0 + kk];
    }
    __syncthreads();
    float r0 = win[tl+k0+0], r1 = win[tl+k0+1], r2 = win[tl+k0+2], r3 = win[tl+k0+3];
    #pragma unroll 4
    for (int kk = 0; kk < 32; ++kk){
      float fv[8];
      *(float4*)&fv[0] = *(const float4*)&fbl[kk][cg*8];
      *(float4*)&fv[4] = *(const float4*)&fbl[kk][cg*8+4];
      #pragma unroll
      for (int i=0;i<8;++i){
        acc[i][0] = fmaf(fv[i], r0, acc[i][0]);
        acc[i][1] = fmaf(fv[i], r1, acc[i][1]);
        acc[i][2] = fmaf(fv[i], r2, acc[i][2]);
        acc[i][3] = fmaf(fv[i], r3, acc[i][3]);
      }
      r0=r1; r1=r2; r2=r3; r3 = win[tl+k0+kk+4];
    }
  }
  #pragma unroll
  for (int i=0;i<8;++i){
    int c = c0 + cg*8 + i;
    float4 v; v.x=acc[i][0]; v.y=acc[i][1]; v.z=acc[i][2]; v.w=acc[i][3];
    *(float4*)&spec[(size_t)(b*NC+c)*NT + t0 + tl] = v;
  }
}

// ============ K2: dilated residual conv layer (enc & dec) ============
// mode 0 (enc, pad-right): h[t] = W0 x[t]   + W1 x[t+d]
// mode 1 (dec, pad-left) : h[t] = W0 x[t-d] + W1 x[t]
// out = in + leaky_relu(h + bias, 0.2)
__global__ __launch_bounds__(256,2) void k_dil(const float* __restrict__ xin,
                                               float* __restrict__ xout,
                                               const float* __restrict__ W,    // [co][ci][2]
                                               const float* __restrict__ bias, // [co]
                                               int d, int mode){
  const int t0 = blockIdx.x * 256;
  const int b  = blockIdx.y;
  __shared__ float wl[2][16][132];
  __shared__ float xl[2][16][260];
  const int tid = threadIdx.x;
  const int cg = tid & 15;
  const int tg = tid >> 4;
  const int o0 = (mode==0) ? 0 : -d;
  const int o1 = (mode==0) ? d : 0;
  float acc[8][16];
  #pragma unroll
  for (int i=0;i<8;++i){
    #pragma unroll
    for (int j=0;j<16;++j) acc[i][j]=0.0f;
  }
  for (int ci0 = 0; ci0 < NC; ci0 += 16){
    __syncthreads();
    #pragma unroll
    for (int i=0;i<16;++i){
      int flat = i*256 + tid;
      int co = flat >> 5;
      int r  = flat & 31;
      wl[r & 1][r >> 1][co] = W[co*256 + (ci0 + (r>>1))*2 + (r & 1)];
    }
    #pragma unroll
    for (int i=0;i<32;++i){
      int flat = i*256 + tid;
      int p   = flat >> 12;
      int rem = flat & 4095;
      int cc  = rem >> 8;
      int j   = rem & 255;
      int t = t0 + ((p==0) ? o0 : o1) + j;
      xl[p][cc][j] = (t >= 0 && t < NT) ? xin[(size_t)(b*NC + ci0 + cc)*NT + t] : 0.0f;
    }
    __syncthreads();
    #pragma unroll 2
    for (int cc=0; cc<16; ++cc){
      float w0[8], w1[8], x0[16], x1[16];
      *(float4*)&w0[0] = *(const float4*)&wl[0][cc][cg*4];
      *(float4*)&w0[4] = *(const float4*)&wl[0][cc][64 + cg*4];
      *(float4*)&w1[0] = *(const float4*)&wl[1][cc][cg*4];
      *(float4*)&w1[4] = *(const float4*)&wl[1][cc][64 + cg*4];
      #pragma unroll
      for (int m=0;m<4;++m){
        *(float4*)&x0[m*4] = *(const float4*)&xl[0][cc][tg*16 + m*4];
        *(float4*)&x1[m*4] = *(const float4*)&xl[1][cc][tg*16 + m*4];
      }
      #pragma unroll
      for (int i=0;i<8;++i){
        #pragma unroll
        for (int j=0;j<16;++j)
          acc[i][j] = fmaf(w0[i], x0[j], fmaf(w1[i], x1[j], acc[i][j]));
      }
    }
  }
  #pragma unroll
  for (int i=0;i<8;++i){
    int co = (i < 4) ? (cg*4 + i) : (64 + cg*4 + (i-4));
    float bv = bias[co];
    const float* xr = &xin[(size_t)(b*NC+co)*NT + t0 + tg*16];
    float* xw = &xout[(size_t)(b*NC+co)*NT + t0 + tg*16];
    #pragma unroll
    for (int m=0;m<4;++m){
      float4 xv = *(const float4*)&xr[m*4];
      float h0 = acc[i][m*4+0] + bv; h0 = (h0 >= 0.f) ? h0 : 0.2f*h0;
      float h1 = acc[i][m*4+1] + bv; h1 = (h1 >= 0.f) ? h1 : 0.2f*h1;
      float h2 = acc[i][m*4+2] + bv; h2 = (h2 >= 0.f) ? h2 : 0.2f*h2;
      float h3 = acc[i][m*4+3] + bv; h3 = (h3 >= 0.f) ? h3 : 0.2f*h3;
      float4 ov; ov.x = xv.x + h0; ov.y = xv.y + h1; ov.z = xv.z + h2; ov.w = xv.w + h3;
      *(float4*)&xw[m*4] = ov;
    }
  }
}

// ============ K3a: up-proj on t-subsample (t = 32*i), store keys + coarse hist ============
__global__ __launch_bounds__(256) void k_sub(const float* __restrict__ enc,
                                             const float* __restrict__ upw,
                                             const float* __restrict__ upb,
                                             u32* __restrict__ keys,
                                             u32* __restrict__ hist1){
  const int u0 = blockIdx.x * 64;
  const int i0 = blockIdx.y * 256;
  const int b  = blockIdx.z;
  __shared__ float uwl[32][68];
  __shared__ float ec[32][260];
  __shared__ u32 lh[1024];
  const int tid = threadIdx.x;
  for (int i=tid;i<1024;i+=256) lh[i] = 0u;
  const int ug = tid & 15;
  const int ig = tid >> 4;
  float acc[4][16];
  #pragma unroll
  for (int i=0;i<4;++i){
    #pragma unroll
    for (int j=0;j<16;++j) acc[i][j]=0.0f;
  }
  for (int c0=0;c0<NC;c0+=32){
    __syncthreads();
    #pragma unroll
    for (int i=0;i<8;++i){
      int flat = i*256+tid;
      uwl[flat & 31][flat >> 5] = upw[(size_t)(u0 + (flat>>5))*NC + c0 + (flat&31)];
    }
    #pragma unroll
    for (int i=0;i<32;++i){
      int flat = i*256+tid;
      ec[flat >> 8][flat & 255] = enc[(size_t)(b*NC + c0 + (flat>>8))*NT + (size_t)(i0 + (flat&255))*32];
    }
    __syncthreads();
    #pragma unroll 2
    for (int cc=0;cc<32;++cc){
      float a[4], bb[16];
      *(float4*)&a[0] = *(const float4*)&uwl[cc][ug*4];
      #pragma unroll
      for (int m=0;m<4;++m)
        *(float4*)&bb[m*4] = *(const float4*)&ec[cc][ig*16 + m*4];
      #pragma unroll
      for (int i=0;i<4;++i){
        #pragma unroll
        for (int j=0;j<16;++j)
          acc[i][j] = fmaf(a[i], bb[j], acc[i][j]);
      }
    }
  }
  #pragma unroll
  for (int i=0;i<4;++i){
    int u = u0 + ug*4 + i;
    float ub = upb[u];
    #pragma unroll
    for (int j=0;j<16;++j){
      float v = acc[i][j] + ub;
      u32 k = f2key(v);
      keys[(size_t)(b*NUP + u)*1024 + i0 + ig*16 + j] = k;
      atomicAdd(&lh[k >> 22], 1u);
    }
  }
  __syncthreads();
  for (int i=tid;i<1024;i+=256){
    u32 c = lh[i];
    if (c) atomicAdd(&hist1[b*1024 + i], c);
  }
}

// ============ K3sel: suffix-scan a 1024-bin histogram, pick rank-64 bin ============
__global__ __launch_bounds__(256) void k_sel(const u32* __restrict__ hist,
                                             u32* __restrict__ cstar,
                                             u32* __restrict__ nab,
                                             u32* __restrict__ t0key,
                                             int phase){
  const int b = blockIdx.x;
  __shared__ u32 s1[1024];
  __shared__ u32 s2[1024];
  __shared__ int red[256];
  const int tid = threadIdx.x;
  for (int i=tid;i<1024;i+=256) s1[i] = hist[b*1024 + i];
  __syncthreads();
  u32* cur = s1; u32* nxt = s2;
  for (int off=1; off<1024; off<<=1){
    for (int i=tid;i<1024;i+=256){
      u32 v = cur[i];
      if (i + off < 1024) v += cur[i+off];
      nxt[i] = v;
    }
    __syncthreads();
    u32* t = cur; cur = nxt; nxt = t;
  }
  u32 off0 = (phase==1) ? 0u : nab[b];
  int best = -1;
  for (int i=tid;i<1024;i+=256)
    if (off0 + cur[i] >= 64u && i > best) best = i;
  red[tid] = best;
  __syncthreads();
  for (int st=128; st>0; st>>=1){
    if (tid < st) red[tid] = max(red[tid], red[tid+st]);
    __syncthreads();
  }
  if (tid == 0){
    int bi = (red[0] < 0) ? 0 : red[0];
    if (phase == 1){
      cstar[b] = (u32)bi;
      nab[b] = (bi < 1023) ? cur[bi+1] : 0u;
    } else {
      t0key[b] = (cstar[b] << 22) | (((u32)bi) << 12);
    }
  }
}

// ============ K3h2: fine histogram within coarse bin ============
__global__ void k_h2(const u32* __restrict__ keys, const u32* __restrict__ cstar,
                     u32* __restrict__ hist2){
  const u32 c0 = cstar[0], c1 = cstar[1];
  int i = blockIdx.x*256 + threadIdx.x;
  const int total = NB*NUP*1024;
  const int stride = gridDim.x*256;
  for (; i < total; i += stride){
    u32 k = keys[i];
    u32 cs = (i >> 21) ? c1 : c0;
    if ((k >> 22) == cs) atomicAdd(&hist2[((u32)(i>>21)<<10) + ((k>>12) & 1023u)], 1u);
  }
}

// ============ K3b: full up-proj GEMM, append candidates >= threshold ============
__global__ __launch_bounds__(256,2) void k_up(const float* __restrict__ enc,
                                              const float* __restrict__ upw,
                                              const float* __restrict__ upb,
                                              const u32* __restrict__ t0key,
                                              float* __restrict__ cval,
                                              int*  __restrict__ cidx,
                                              int*  __restrict__ counts){
  const int u0 = blockIdx.x * 128;
  const int t0 = blockIdx.y * 256;
  const int b  = blockIdx.z;
  __shared__ float uwl[32][132];
  __shared__ float ec[32][260];
  const int tid = threadIdx.x;
  const int ug = tid & 15;
  const int tg = tid >> 4;
  float acc[8][16];
  #pragma unroll
  for (int i=0;i<8;++i){
    #pragma unroll
    for (int j=0;j<16;++j) acc[i][j]=0.0f;
  }
  for (int c0=0;c0<NC;c0+=32){
    __syncthreads();
    #pragma unroll
    for (int i=0;i<16;++i){
      int flat = i*256+tid;
      uwl[flat & 31][flat >> 5] = upw[(size_t)(u0 + (flat>>5))*NC + c0 + (flat&31)];
    }
    #pragma unroll
    for (int i=0;i<32;++i){
      int flat = i*256+tid;
      ec[flat >> 8][flat & 255] = enc[(size_t)(b*NC + c0 + (flat>>8))*NT + t0 + (flat&255)];
    }
    __syncthreads();
    #pragma unroll 2
    for (int cc=0;cc<32;++cc){
      float a[8], bb[16];
      *(float4*)&a[0] = *(const float4*)&uwl[cc][ug*4];
      *(float4*)&a[4] = *(const float4*)&uwl[cc][64 + ug*4];
      #pragma unroll
      for (int m=0;m<4;++m)
        *(float4*)&bb[m*4] = *(const float4*)&ec[cc][tg*16 + m*4];
      #pragma unroll
      for (int i=0;i<8;++i){
        #pragma unroll
        for (int j=0;j<16;++j)
          acc[i][j] = fmaf(a[i], bb[j], acc[i][j]);
      }
    }
  }
  const float T0 = key2f(t0key[b]);
  #pragma unroll
  for (int i=0;i<8;++i){
    int u = u0 + ((i<4) ? (ug*4 + i) : (64 + ug*4 + (i-4)));
    float ub = upb[u];
    #pragma unroll
    for (int j=0;j<16;++j){
      float v = acc[i][j] + ub;
      if (v >= T0){
        int slot = atomicAdd(&counts[b], 1);
        if (slot < CAP){
          cval[b*CAP + slot] = v;
          cidx[b*CAP + slot] = u*NT + (t0 + tg*16 + j);
        }
      }
    }
  }
}

// ============ K3c: exact top-64 of candidates ============
__global__ __launch_bounds__(256) void k_top(const float* __restrict__ cval,
                                             const int* __restrict__ cidx,
                                             const int* __restrict__ counts,
                                             float* __restrict__ tv,
                                             int* __restrict__ ti){
  const int b = blockIdx.x;
  __shared__ float lv[CAP];
  __shared__ float sv[256];
  __shared__ int   si[256];
  const int tid = threadIdx.x;
  int n = counts[b]; if (n > CAP) n = CAP;
  for (int i=tid;i<n;i+=256) lv[i] = cval[b*CAP+i];
  __syncthreads();
  for (int r=0;r<64;++r){
    float best = -3.4e38f; int bi = -1;
    for (int i=tid;i<n;i+=256){
      float v = lv[i];
      if (v > best){ best = v; bi = i; }
    }
    sv[tid]=best; si[tid]=bi;
    __syncthreads();
    for (int st=128; st>0; st>>=1){
      if (tid < st && sv[tid+st] > sv[tid]){ sv[tid]=sv[tid+st]; si[tid]=si[tid+st]; }
      __syncthreads();
    }
    if (tid == 0){
      int kb = si[0];
      if (kb >= 0){
        tv[b*64+r] = sv[0];
        ti[b*64+r] = cidx[b*CAP+kb];
        lv[kb] = -3.4e38f;
      } else { tv[b*64+r] = 0.0f; ti[b*64+r] = 0; }
    }
    __syncthreads();
  }
}

// ============ K4a: fill decoder input with down_b ============
__global__ void k_fill(float* __restrict__ dst, const float* __restrict__ downb){
  const int bc = blockIdx.x;            // b*128+c
  const int c = bc & 127;
  float v = downb[c];
  float4 vv; vv.x=v; vv.y=v; vv.z=v; vv.w=v;
  float4* p = (float4*)(dst + (size_t)bc*NT);
  for (int i=threadIdx.x; i < NT/4; i += 256) p[i] = vv;
}

// ============ K4b: scatter spikes through down_w ============
__global__ void k_scat(float* __restrict__ dst, const float* __restrict__ downw,
                       const float* __restrict__ tv, const int* __restrict__ ti){
  const int b = blockIdx.x, r = blockIdx.y;
  float v = tv[b*64+r];
  int idx = ti[b*64+r];
  int u = idx / NT, t = idx - u*NT;
  int c = threadIdx.x;   // 128 threads
  atomicAdd(&dst[(size_t)(b*NC+c)*NT + t], downw[(size_t)c*NUP + u] * v);
}

// ============ K6: transposed filterbank synthesis (partials over c-chunks) ============
// final[b,t] = sum_c sum_{j<512} fb[c,j] * dec[b,c,t+256-j]   (dec zero outside [0,N))
#define TS 4096
__global__ __launch_bounds__(256) void k_syn(const float* __restrict__ dec,
                                             const float* __restrict__ fb,
                                             float* __restrict__ part){
  const int ts = blockIdx.x;    // 8
  const int cs = blockIdx.y;    // 16
  const int b  = blockIdx.z;
  const int t0 = ts * TS;
  __shared__ float win[4 + TS + 511 + 8];
  __shared__ float fbl[512];
  const int tid = threadIdx.x;
  const int tl = tid * 16;
  float acc[16];
  #pragma unroll
  for (int j=0;j<16;++j) acc[j] = 0.0f;
  for (int c = cs*8; c < cs*8+8; ++c){
    __syncthreads();
    for (int i=tid; i < TS+511; i += 256){
      int t = t0 - 255 + i;
      win[4+i] = (t >= 0 && t < NT) ? dec[(size_t)(b*NC+c)*NT + t] : 0.0f;
    }
    for (int i=tid; i<512; i+=256) fbl[i] = fb[c*KFB + i];
    __syncthreads();
    float w[23];
    #pragma unroll
    for (int k=0;k<23;++k) w[k] = win[4 + tl + 504 + k];
    for (int G=0; G<64; ++G){
      float4 f0 = *(const float4*)&fbl[G*8];
      float4 f1 = *(const float4*)&fbl[G*8+4];
      float fq[8] = {f0.x, f0.y, f0.z, f0.w, f1.x, f1.y, f1.z, f1.w};
      #pragma unroll
      for (int q=0;q<8;++q){
        #pragma unroll
        for (int jj=0;jj<16;++jj)
          acc[jj] = fmaf(fq[q], w[7-q+jj], acc[jj]);
      }
      if (G != 63){
        #pragma unroll
        for (int k=22;k>=8;--k) w[k] = w[k-8];
        #pragma unroll
        for (int k=0;k<8;++k) w[k] = win[4 + tl + 496 - 8*G + k];
      }
    }
  }
  float* po = &part[(size_t)(cs*NB + b)*NT + t0 + tl];
  #pragma unroll
  for (int m=0;m<4;++m){
    float4 ov; ov.x=acc[m*4+0]; ov.y=acc[m*4+1]; ov.z=acc[m*4+2]; ov.w=acc[m*4+3];
    *(float4*)&po[m*4] = ov;
  }
}

// ============ K6r: reduce partials -> out ============
__global__ void k_red(const float* __restrict__ part, float* __restrict__ out){
  int i = blockIdx.x*256 + threadIdx.x;  // grid 256 -> 65536
  float s = 0.0f;
  #pragma unroll
  for (int cs=0;cs<16;++cs) s += part[(size_t)cs*(NB*NT) + i];
  out[i] = s;
}

extern "C" void kernel_launch(void* const* d_in, const int* in_sizes, int n_in,
                              void* d_out, int out_size, void* d_ws, size_t ws_size,
                              hipStream_t stream){
  const float* x    = (const float*)d_in[0];
  const float* fb   = (const float*)d_in[1];
  const float* encw = (const float*)d_in[2];
  const float* encb = (const float*)d_in[3];
  const float* upw  = (const float*)d_in[4];
  const float* upb  = (const float*)d_in[5];
  const float* dnw  = (const float*)d_in[6];
  const float* dnb  = (const float*)d_in[7];
  const float* decw = (const float*)d_in[8];
  const float* decb = (const float*)d_in[9];
  float* out = (float*)d_out;
  char* ws = (char*)d_ws;

  size_t o = 0;
  float* bufA = (float*)(ws + o); o += (size_t)NB*NC*NT*4;      // 33.55 MB
  float* bufB = (float*)(ws + o); o += (size_t)NB*NC*NT*4;      // 33.55 MB
  u32*  keys  = (u32*)(ws + o);   o += (size_t)NB*NUP*1024*4;   // 16.78 MB
  u32*  hist1 = (u32*)(ws + o);   o += 1024*NB*4;
  u32*  hist2 = (u32*)(ws + o);   o += 1024*NB*4;
  u32*  cstar = (u32*)(ws + o);   o += 64;
  u32*  nab   = (u32*)(ws + o);   o += 64;
  u32*  t0k   = (u32*)(ws + o);   o += 64;
  int*  cnt   = (int*)(ws + o);   o += 64;
  float* tv   = (float*)(ws + o); o += NB*64*4;
  int*  ti    = (int*)(ws + o);   o += NB*64*4;
  float* cval = (float*)(ws + o); o += (size_t)NB*CAP*4;
  int*  cidx  = (int*)(ws + o);   o += (size_t)NB*CAP*4;
  float* part = (float*)(ws + o); o += (size_t)16*NB*NT*4;      // 4.19 MB
  // total ~88.4 MB

  static const int dil[6] = {1,3,9,27,81,1};

  k_init<<<dim3(16), dim3(256), 0, stream>>>(hist1, hist2, cnt);
  k_fb<<<dim3(256,2,NB), dim3(256), 0, stream>>>(x, fb, bufA);

  float* src = bufA; float* dst = bufB;
  for (int l=0;l<6;++l){
    k_dil<<<dim3(128,NB), dim3(256), 0, stream>>>(src, dst, encw + (size_t)l*NC*NC*2, encb + l*NC, dil[l], 0);
    float* t = src; src = dst; dst = t;
  }
  // encoder output now in src == bufA

  k_sub<<<dim3(32,4,NB), dim3(256), 0, stream>>>(src, upw, upb, keys, hist1);
  k_sel<<<dim3(NB), dim3(256), 0, stream>>>(hist1, cstar, nab, t0k, 1);
  k_h2 <<<dim3(4096), dim3(256), 0, stream>>>(keys, cstar, hist2);
  k_sel<<<dim3(NB), dim3(256), 0, stream>>>(hist2, cstar, nab, t0k, 2);
  k_up <<<dim3(16,128,NB), dim3(256), 0, stream>>>(src, upw, upb, t0k, cval, cidx, cnt);
  k_top<<<dim3(NB), dim3(256), 0, stream>>>(cval, cidx, cnt, tv, ti);

  k_fill<<<dim3(NB*NC), dim3(256), 0, stream>>>(bufB, dnb);
  k_scat<<<dim3(NB,64), dim3(128), 0, stream>>>(bufB, dnw, tv, ti);

  src = bufB; dst = bufA;
  for (int l=0;l<6;++l){
    k_dil<<<dim3(128,NB), dim3(256), 0, stream>>>(src, dst, decw + (size_t)l*NC*NC*2, decb + l*NC, dil[l], 1);
    float* t = src; src = dst; dst = t;
  }
  // decoder output now in src == bufB

  k_syn<<<dim3(8,16,NB), dim3(256), 0, stream>>>(src, fb, part);
  k_red<<<dim3(256), dim3(256), 0, stream>>>(part, out);
}

// Round 2
// 1390.360 us; speedup vs baseline: 1.8181x; 1.8181x over previous
//
#include <hip/hip_runtime.h>
#include <stdint.h>

#define NB  2
#define NC  128
#define NT  32768
#define KFB 512
#define NUP 2048
#define CAP 14336

typedef unsigned int u32;
typedef unsigned short u16;
typedef short s16;
typedef float f32x4 __attribute__((ext_vector_type(4)));
typedef s16 short8 __attribute__((ext_vector_type(8)));
typedef u32 u32x4 __attribute__((ext_vector_type(4)));

__device__ __forceinline__ u32 f2key(float v){
  u32 u = __float_as_uint(v);
  return (u & 0x80000000u) ? ~u : (u | 0x80000000u);
}
__device__ __forceinline__ float key2f(u32 k){
  u32 u = (k & 0x80000000u) ? (k & 0x7FFFFFFFu) : ~k;
  return __uint_as_float(u);
}
__device__ __forceinline__ u16 bf16rn(float v){
  u32 u = __float_as_uint(v);
  return (u16)((u + 0x7FFFu + ((u>>16)&1u)) >> 16);
}

// ============ K0: init (zero histograms + counters) ============
__global__ void k_init(u32* __restrict__ h1, u32* __restrict__ h2, int* __restrict__ counts){
  int i = blockIdx.x*256 + threadIdx.x;
  if (i < 2048) h1[i] = 0u;
  else if (i < 4096) h2[i-2048] = 0u;
  if (i < NB) counts[i] = 0;
}

// ============ K_prep: split weights to bf16 hi/lo in MFMA A-fragment order ============
// dil layout: [layer 12][s 8][mt 8][p {hi,lo}][lane 64][j 8]  (unit = (layer*8+s)*8+mt, stride 1024 u16)
//   A[m][k]: m = mt*16 + (lane&15), k = s*32 + (lane>>4)*8 + j;  k -> tap=k>>7, ci=k&127
// up layout:  [s 4][umt 128][p][lane][j]  (unit = s*128+umt), k = ci
__global__ __launch_bounds__(256) void k_prep(const float* __restrict__ encw,
    const float* __restrict__ decw, const float* __restrict__ upw,
    u16* __restrict__ wdil, u16* __restrict__ wup){
  int g = blockIdx.x*256 + threadIdx.x;
  if (g < 49152){
    int l = g & 63, mt = (g>>6)&7, s = (g>>9)&7, layer = g>>12;
    const float* W = (layer < 6) ? (encw + (size_t)layer*NC*NC*2)
                                 : (decw + (size_t)(layer-6)*NC*NC*2);
    int co = mt*16 + (l & 15);
    int kb = s*32 + ((l>>4)<<3);
    union { u16 h[8]; u32x4 q; } H, L;
    #pragma unroll
    for (int j=0;j<8;++j){
      int k = kb + j;
      float v = W[((size_t)co*NC + (k&127))*2 + (k>>7)];
      u16 h = bf16rn(v);
      H.h[j] = h;
      L.h[j] = bf16rn(v - __uint_as_float(((u32)h)<<16));
    }
    int unit = g >> 6;
    *(u32x4*)(wdil + (size_t)unit*1024 + (l<<3)) = H.q;
    *(u32x4*)(wdil + (size_t)unit*1024 + 512 + (l<<3)) = L.q;
  } else if (g < 81920){
    int g2 = g - 49152;
    int l = g2 & 63, umt = (g2>>6)&127, s = g2>>13;
    int u = umt*16 + (l & 15);
    int kb = s*32 + ((l>>4)<<3);
    union { u16 h[8]; u32x4 q; } H, L;
    #pragma unroll
    for (int j=0;j<8;++j){
      float v = upw[(size_t)u*NC + kb + j];
      u16 h = bf16rn(v);
      H.h[j] = h;
      L.h[j] = bf16rn(v - __uint_as_float(((u32)h)<<16));
    }
    int unit = g2 >> 6;
    *(u32x4*)(wup + (size_t)unit*1024 + (l<<3)) = H.q;
    *(u32x4*)(wup + (size_t)unit*1024 + 512 + (l<<3)) = L.q;
  }
}

// ============ K1: filterbank analysis (fp32 vector, unchanged) ============
__global__ __launch_bounds__(256) void k_fb(const float* __restrict__ x,
                                            const float* __restrict__ fb,
                                            float* __restrict__ spec){
  const int t0 = blockIdx.x * 128;
  const int c0 = blockIdx.y * 64;
  const int b  = blockIdx.z;
  __shared__ float win[640];
  __shared__ float fbl[32][64];
  const int tid = threadIdx.x;
  for (int j = tid; j < 640; j += 256){
    int t = t0 - 256 + j;
    win[j] = (t >= 0 && t < NT) ? x[b*NT + t] : 0.0f;
  }
  const int cg = tid & 7;
  const int tl = (tid >> 3) * 4;
  float acc[8][4];
  #pragma unroll
  for (int i=0;i<8;++i){
    #pragma unroll
    for (int j=0;j<4;++j) acc[i][j]=0.0f;
  }
  for (int k0 = 0; k0 < KFB; k0 += 32){
    __syncthreads();
    #pragma unroll
    for (int r = 0; r < 8; ++r){
      int flat = r*256 + tid;
      int kk = flat >> 6, c = flat & 63;
      fbl[kk][c] = fb[(c0+c)*KFB + k0 + kk];
    }
    __syncthreads();
    float r0 = win[tl+k0+0], r1 = win[tl+k0+1], r2 = win[tl+k0+2], r3 = win[tl+k0+3];
    #pragma unroll 4
    for (int kk = 0; kk < 32; ++kk){
      float fv[8];
      *(float4*)&fv[0] = *(const float4*)&fbl[kk][cg*8];
      *(float4*)&fv[4] = *(const float4*)&fbl[kk][cg*8+4];
      #pragma unroll
      for (int i=0;i<8;++i){
        acc[i][0] = fmaf(fv[i], r0, acc[i][0]);
        acc[i][1] = fmaf(fv[i], r1, acc[i][1]);
        acc[i][2] = fmaf(fv[i], r2, acc[i][2]);
        acc[i][3] = fmaf(fv[i], r3, acc[i][3]);
      }
      r0=r1; r1=r2; r2=r3; r3 = win[tl+k0+kk+4];
    }
  }
  #pragma unroll
  for (int i=0;i<8;++i){
    int c = c0 + cg*8 + i;
    float4 v; v.x=acc[i][0]; v.y=acc[i][1]; v.z=acc[i][2]; v.w=acc[i][3];
    *(float4*)&spec[(size_t)(b*NC+c)*NT + t0 + tl] = v;
  }
}

// ============ K2: dilated residual conv layer — bf16x3 MFMA ============
// mode 0 (enc): h[t] = W0 x[t] + W1 x[t+d];  mode 1 (dec): h[t] = W0 x[t-d] + W1 x[t]
// out = xin + leaky_relu(h + bias, 0.2).  Block: co 128 x t 128. Waves 2x2.
__global__ __launch_bounds__(256,2) void k_dil(const float* __restrict__ xin,
    float* __restrict__ xout, const u16* __restrict__ wf,
    const float* __restrict__ bias, int d, int mode){
  __shared__ u32 lx[212*32];          // [t][ci^swz] packed (hi<<16)|lo
  const int tid = threadIdx.x;
  const int b  = blockIdx.y;
  const int t0 = blockIdx.x << 7;
  const int base = mode ? -d : 0;
  const int lane = tid & 63, w = tid >> 6;
  const int wy = w >> 1, wx = w & 1;
  const int quad = lane >> 4, l15 = lane & 15;
  const int ci_l = tid >> 3, sub = tid & 7;
  f32x4 acc[4][4] = {};
  const float* xb = xin + (size_t)b*NC*NT;
  for (int cc = 0; cc < 4; ++cc){
    __syncthreads();
    const float* xr = xb + (size_t)(cc*32 + ci_l)*NT;
    #pragma unroll
    for (int j=0;j<27;++j){
      int tl = sub + (j<<3);
      if (tl < 212){
        int tg = t0 + base + tl;
        float v = ((u32)tg < (u32)NT) ? xr[tg] : 0.0f;
        u16 h = bf16rn(v);
        u16 lo = bf16rn(v - __uint_as_float(((u32)h)<<16));
        lx[(tl<<5) + (ci_l ^ ((tl&3)<<3))] = ((u32)h<<16) | lo;
      }
    }
    __syncthreads();
    #pragma unroll
    for (int tap = 0; tap < 2; ++tap){
      const int off = tap ? d : 0;
      const int s = (tap<<2) + cc;
      short8 ah[4], al[4];
      #pragma unroll
      for (int mt=0; mt<4; ++mt){
        const u16* p = wf + (size_t)(s*8 + wy*4 + mt)*1024 + (lane<<3);
        ah[mt] = *(const short8*)p;
        al[mt] = *(const short8*)(p + 512);
      }
      short8 xh[4], xl[4];
      #pragma unroll
      for (int nt=0; nt<4; ++nt){
        int T = off + (wx<<6) + (nt<<4) + l15;
        int idx = (T<<5) + ((quad<<3) ^ ((T&3)<<3));
        u32x4 r0 = *(const u32x4*)&lx[idx];
        u32x4 r1 = *(const u32x4*)&lx[idx+4];
        union { u32 u[4]; short8 v; } H, L;
        H.u[0] = __builtin_amdgcn_perm(r0.y, r0.x, 0x07060302u);
        H.u[1] = __builtin_amdgcn_perm(r0.w, r0.z, 0x07060302u);
        H.u[2] = __builtin_amdgcn_perm(r1.y, r1.x, 0x07060302u);
        H.u[3] = __builtin_amdgcn_perm(r1.w, r1.z, 0x07060302u);
        L.u[0] = __builtin_amdgcn_perm(r0.y, r0.x, 0x05040100u);
        L.u[1] = __builtin_amdgcn_perm(r0.w, r0.z, 0x05040100u);
        L.u[2] = __builtin_amdgcn_perm(r1.y, r1.x, 0x05040100u);
        L.u[3] = __builtin_amdgcn_perm(r1.w, r1.z, 0x05040100u);
        xh[nt] = H.v; xl[nt] = L.v;
      }
      #pragma unroll
      for (int mt=0; mt<4; ++mt){
        #pragma unroll
        for (int nt=0; nt<4; ++nt){
          acc[mt][nt] = __builtin_amdgcn_mfma_f32_16x16x32_bf16(ah[mt], xh[nt], acc[mt][nt], 0,0,0);
          acc[mt][nt] = __builtin_amdgcn_mfma_f32_16x16x32_bf16(ah[mt], xl[nt], acc[mt][nt], 0,0,0);
          acc[mt][nt] = __builtin_amdgcn_mfma_f32_16x16x32_bf16(al[mt], xh[nt], acc[mt][nt], 0,0,0);
        }
      }
    }
  }
  #pragma unroll
  for (int mt=0; mt<4; ++mt){
    #pragma unroll
    for (int r=0; r<4; ++r){
      const int co = (wy<<6) + (mt<<4) + (quad<<2) + r;
      const float bv = bias[co];
      const float* xi = xb + (size_t)co*NT + t0 + (wx<<6) + l15;
      float* xo = xout + (size_t)(b*NC+co)*NT + t0 + (wx<<6) + l15;
      #pragma unroll
      for (int nt=0; nt<4; ++nt){
        float h = acc[mt][nt][r] + bv;
        h = (h >= 0.f) ? h : 0.2f*h;
        xo[nt<<4] = xi[nt<<4] + h;
      }
    }
  }
}

// ============ K3a: up-proj on t-subsample (t = 32*i), fp32, keys + coarse hist ============
__global__ __launch_bounds__(256) void k_sub(const float* __restrict__ enc,
                                             const float* __restrict__ upw,
                                             const float* __restrict__ upb,
                                             u32* __restrict__ keys,
                                             u32* __restrict__ hist1){
  const int u0 = blockIdx.x * 64;
  const int i0 = blockIdx.y * 256;
  const int b  = blockIdx.z;
  __shared__ float uwl[32][68];
  __shared__ float ec[32][260];
  __shared__ u32 lh[1024];
  const int tid = threadIdx.x;
  for (int i=tid;i<1024;i+=256) lh[i] = 0u;
  const int ug = tid & 15;
  const int ig = tid >> 4;
  float acc[4][16];
  #pragma unroll
  for (int i=0;i<4;++i){
    #pragma unroll
    for (int j=0;j<16;++j) acc[i][j]=0.0f;
  }
  for (int c0=0;c0<NC;c0+=32){
    __syncthreads();
    #pragma unroll
    for (int i=0;i<8;++i){
      int flat = i*256+tid;
      uwl[flat & 31][flat >> 5] = upw[(size_t)(u0 + (flat>>5))*NC + c0 + (flat&31)];
    }
    #pragma unroll
    for (int i=0;i<32;++i){
      int flat = i*256+tid;
      ec[flat >> 8][flat & 255] = enc[(size_t)(b*NC + c0 + (flat>>8))*NT + (size_t)(i0 + (flat&255))*32];
    }
    __syncthreads();
    #pragma unroll 2
    for (int cc=0;cc<32;++cc){
      float a[4], bb[16];
      *(float4*)&a[0] = *(const float4*)&uwl[cc][ug*4];
      #pragma unroll
      for (int m=0;m<4;++m)
        *(float4*)&bb[m*4] = *(const float4*)&ec[cc][ig*16 + m*4];
      #pragma unroll
      for (int i=0;i<4;++i){
        #pragma unroll
        for (int j=0;j<16;++j)
          acc[i][j] = fmaf(a[i], bb[j], acc[i][j]);
      }
    }
  }
  #pragma unroll
  for (int i=0;i<4;++i){
    int u = u0 + ug*4 + i;
    float ub = upb[u];
    #pragma unroll
    for (int j=0;j<16;++j){
      float v = acc[i][j] + ub;
      u32 k = f2key(v);
      keys[(size_t)(b*NUP + u)*1024 + i0 + ig*16 + j] = k;
      atomicAdd(&lh[k >> 22], 1u);
    }
  }
  __syncthreads();
  for (int i=tid;i<1024;i+=256){
    u32 c = lh[i];
    if (c) atomicAdd(&hist1[b*1024 + i], c);
  }
}

// ============ K3sel: suffix-scan histogram, pick rank-64 bin ============
__global__ __launch_bounds__(256) void k_sel(const u32* __restrict__ hist,
                                             u32* __restrict__ cstar,
                                             u32* __restrict__ nab,
                                             u32* __restrict__ t0key,
                                             int phase){
  const int b = blockIdx.x;
  __shared__ u32 s1[1024];
  __shared__ u32 s2[1024];
  __shared__ int red[256];
  const int tid = threadIdx.x;
  for (int i=tid;i<1024;i+=256) s1[i] = hist[b*1024 + i];
  __syncthreads();
  u32* cur = s1; u32* nxt = s2;
  for (int off=1; off<1024; off<<=1){
    for (int i=tid;i<1024;i+=256){
      u32 v = cur[i];
      if (i + off < 1024) v += cur[i+off];
      nxt[i] = v;
    }
    __syncthreads();
    u32* t = cur; cur = nxt; nxt = t;
  }
  u32 off0 = (phase==1) ? 0u : nab[b];
  int best = -1;
  for (int i=tid;i<1024;i+=256)
    if (off0 + cur[i] >= 64u && i > best) best = i;
  red[tid] = best;
  __syncthreads();
  for (int st=128; st>0; st>>=1){
    if (tid < st) red[tid] = max(red[tid], red[tid+st]);
    __syncthreads();
  }
  if (tid == 0){
    int bi = (red[0] < 0) ? 0 : red[0];
    if (phase == 1){
      cstar[b] = (u32)bi;
      nab[b] = (bi < 1023) ? cur[bi+1] : 0u;
    } else {
      t0key[b] = (cstar[b] << 22) | (((u32)bi) << 12);
    }
  }
}

// ============ K3h2: fine histogram within coarse bin ============
__global__ void k_h2(const u32* __restrict__ keys, const u32* __restrict__ cstar,
                     u32* __restrict__ hist2){
  const u32 c0 = cstar[0], c1 = cstar[1];
  int i = blockIdx.x*256 + threadIdx.x;
  const int total = NB*NUP*1024;
  const int stride = gridDim.x*256;
  for (; i < total; i += stride){
    u32 k = keys[i];
    u32 cs = (i >> 21) ? c1 : c0;
    if ((k >> 22) == cs) atomicAdd(&hist2[((u32)(i>>21)<<10) + ((k>>12) & 1023u)], 1u);
  }
}

// ============ K3b: full up-proj — bf16x3 MFMA, append candidates >= threshold ============
// Block: u 128 x t 128. Waves 2x2.
__global__ __launch_bounds__(256,2) void k_up(const float* __restrict__ enc,
    const u16* __restrict__ wf, const float* __restrict__ upb,
    const u32* __restrict__ t0key, float* __restrict__ cval,
    int* __restrict__ cidx, int* __restrict__ counts){
  __shared__ u32 lx[128*32];
  const int tid = threadIdx.x;
  const int u0 = blockIdx.x << 7;
  const int t0 = blockIdx.y << 7;
  const int b  = blockIdx.z;
  const int lane = tid & 63, w = tid >> 6;
  const int wy = w >> 1, wx = w & 1;
  const int quad = lane >> 4, l15 = lane & 15;
  const int ci_l = tid >> 3, sub = tid & 7;
  f32x4 acc[4][4] = {};
  for (int cc = 0; cc < 4; ++cc){
    __syncthreads();
    const float* xr = enc + (size_t)(b*NC + cc*32 + ci_l)*NT + t0;
    #pragma unroll
    for (int j=0;j<16;++j){
      int tl = sub + (j<<3);
      float v = xr[tl];
      u16 h = bf16rn(v);
      u16 lo = bf16rn(v - __uint_as_float(((u32)h)<<16));
      lx[(tl<<5) + (ci_l ^ ((tl&3)<<3))] = ((u32)h<<16) | lo;
    }
    __syncthreads();
    short8 ah[4], al[4];
    #pragma unroll
    for (int mt=0; mt<4; ++mt){
      const u16* p = wf + (size_t)(cc*128 + (u0>>4) + wy*4 + mt)*1024 + (lane<<3);
      ah[mt] = *(const short8*)p;
      al[mt] = *(const short8*)(p + 512);
    }
    short8 xh[4], xl[4];
    #pragma unroll
    for (int nt=0; nt<4; ++nt){
      int T = (wx<<6) + (nt<<4) + l15;
      int idx = (T<<5) + ((quad<<3) ^ ((T&3)<<3));
      u32x4 r0 = *(const u32x4*)&lx[idx];
      u32x4 r1 = *(const u32x4*)&lx[idx+4];
      union { u32 u[4]; short8 v; } H, L;
      H.u[0] = __builtin_amdgcn_perm(r0.y, r0.x, 0x07060302u);
      H.u[1] = __builtin_amdgcn_perm(r0.w, r0.z, 0x07060302u);
      H.u[2] = __builtin_amdgcn_perm(r1.y, r1.x, 0x07060302u);
      H.u[3] = __builtin_amdgcn_perm(r1.w, r1.z, 0x07060302u);
      L.u[0] = __builtin_amdgcn_perm(r0.y, r0.x, 0x05040100u);
      L.u[1] = __builtin_amdgcn_perm(r0.w, r0.z, 0x05040100u);
      L.u[2] = __builtin_amdgcn_perm(r1.y, r1.x, 0x05040100u);
      L.u[3] = __builtin_amdgcn_perm(r1.w, r1.z, 0x05040100u);
      xh[nt] = H.v; xl[nt] = L.v;
    }
    #pragma unroll
    for (int mt=0; mt<4; ++mt){
      #pragma unroll
      for (int nt=0; nt<4; ++nt){
        acc[mt][nt] = __builtin_amdgcn_mfma_f32_16x16x32_bf16(ah[mt], xh[nt], acc[mt][nt], 0,0,0);
        acc[mt][nt] = __builtin_amdgcn_mfma_f32_16x16x32_bf16(ah[mt], xl[nt], acc[mt][nt], 0,0,0);
        acc[mt][nt] = __builtin_amdgcn_mfma_f32_16x16x32_bf16(al[mt], xh[nt], acc[mt][nt], 0,0,0);
      }
    }
  }
  float T0 = key2f(t0key[b]);
  T0 -= fabsf(T0)*3e-4f + 1e-5f;   // safety: bf16x3 vs fp32-subsample mismatch
  #pragma unroll
  for (int mt=0; mt<4; ++mt){
    #pragma unroll
    for (int r=0; r<4; ++r){
      int u = u0 + (wy<<6) + (mt<<4) + (quad<<2) + r;
      float ub = upb[u];
      #pragma unroll
      for (int nt=0; nt<4; ++nt){
        float v = acc[mt][nt][r] + ub;
        if (v >= T0){
          int slot = atomicAdd(&counts[b], 1);
          if (slot < CAP){
            cval[b*CAP + slot] = v;
            cidx[b*CAP + slot] = u*NT + (t0 + (wx<<6) + (nt<<4) + l15);
          }
        }
      }
    }
  }
}

// ============ K3c: exact top-64 of candidates ============
__global__ __launch_bounds__(256) void k_top(const float* __restrict__ cval,
                                             const int* __restrict__ cidx,
                                             const int* __restrict__ counts,
                                             float* __restrict__ tv,
                                             int* __restrict__ ti){
  const int b = blockIdx.x;
  __shared__ float lv[CAP];
  __shared__ float sv[256];
  __shared__ int   si[256];
  const int tid = threadIdx.x;
  int n = counts[b]; if (n > CAP) n = CAP;
  for (int i=tid;i<n;i+=256) lv[i] = cval[b*CAP+i];
  __syncthreads();
  for (int r=0;r<64;++r){
    float best = -3.4e38f; int bi = -1;
    for (int i=tid;i<n;i+=256){
      float v = lv[i];
      if (v > best){ best = v; bi = i; }
    }
    sv[tid]=best; si[tid]=bi;
    __syncthreads();
    for (int st=128; st>0; st>>=1){
      if (tid < st && sv[tid+st] > sv[tid]){ sv[tid]=sv[tid+st]; si[tid]=si[tid+st]; }
      __syncthreads();
    }
    if (tid == 0){
      int kb = si[0];
      if (kb >= 0){
        tv[b*64+r] = sv[0];
        ti[b*64+r] = cidx[b*CAP+kb];
        lv[kb] = -3.4e38f;
      } else { tv[b*64+r] = 0.0f; ti[b*64+r] = 0; }
    }
    __syncthreads();
  }
}

// ============ K4a: fill decoder input with down_b ============
__global__ void k_fill(float* __restrict__ dst, const float* __restrict__ downb){
  const int bc = blockIdx.x;
  const int c = bc & 127;
  float v = downb[c];
  float4 vv; vv.x=v; vv.y=v; vv.z=v; vv.w=v;
  float4* p = (float4*)(dst + (size_t)bc*NT);
  for (int i=threadIdx.x; i < NT/4; i += 256) p[i] = vv;
}

// ============ K4b: scatter spikes through down_w ============
__global__ void k_scat(float* __restrict__ dst, const float* __restrict__ downw,
                       const float* __restrict__ tv, const int* __restrict__ ti){
  const int b = blockIdx.x, r = blockIdx.y;
  float v = tv[b*64+r];
  int idx = ti[b*64+r];
  int u = idx / NT, t = idx - u*NT;
  int c = threadIdx.x;
  atomicAdd(&dst[(size_t)(b*NC+c)*NT + t], downw[(size_t)c*NUP + u] * v);
}

// ============ K6: transposed filterbank synthesis (fp32, unchanged) ============
#define TS 4096
__global__ __launch_bounds__(256) void k_syn(const float* __restrict__ dec,
                                             const float* __restrict__ fb,
                                             float* __restrict__ part){
  const int ts = blockIdx.x;
  const int cs = blockIdx.y;
  const int b  = blockIdx.z;
  const int t0 = ts * TS;
  __shared__ float win[4 + TS + 511 + 8];
  __shared__ float fbl[512];
  const int tid = threadIdx.x;
  const int tl = tid * 16;
  float acc[16];
  #pragma unroll
  for (int j=0;j<16;++j) acc[j] = 0.0f;
  for (int c = cs*8; c < cs*8+8; ++c){
    __syncthreads();
    for (int i=tid; i < TS+511; i += 256){
      int t = t0 - 255 + i;
      win[4+i] = (t >= 0 && t < NT) ? dec[(size_t)(b*NC+c)*NT + t] : 0.0f;
    }
    for (int i=tid; i<512; i+=256) fbl[i] = fb[c*KFB + i];
    __syncthreads();
    float w[23];
    #pragma unroll
    for (int k=0;k<23;++k) w[k] = win[4 + tl + 504 + k];
    for (int G=0; G<64; ++G){
      float4 f0 = *(const float4*)&fbl[G*8];
      float4 f1 = *(const float4*)&fbl[G*8+4];
      float fq[8] = {f0.x, f0.y, f0.z, f0.w, f1.x, f1.y, f1.z, f1.w};
      #pragma unroll
      for (int q=0;q<8;++q){
        #pragma unroll
        for (int jj=0;jj<16;++jj)
          acc[jj] = fmaf(fq[q], w[7-q+jj], acc[jj]);
      }
      if (G != 63){
        #pragma unroll
        for (int k=22;k>=8;--k) w[k] = w[k-8];
        #pragma unroll
        for (int k=0;k<8;++k) w[k] = win[4 + tl + 496 - 8*G + k];
      }
    }
  }
  float* po = &part[(size_t)(cs*NB + b)*NT + t0 + tl];
  #pragma unroll
  for (int m=0;m<4;++m){
    float4 ov; ov.x=acc[m*4+0]; ov.y=acc[m*4+1]; ov.z=acc[m*4+2]; ov.w=acc[m*4+3];
    *(float4*)&po[m*4] = ov;
  }
}

// ============ K6r: reduce partials -> out ============
__global__ void k_red(const float* __restrict__ part, float* __restrict__ out){
  int i = blockIdx.x*256 + threadIdx.x;
  float s = 0.0f;
  #pragma unroll
  for (int cs=0;cs<16;++cs) s += part[(size_t)cs*(NB*NT) + i];
  out[i] = s;
}

extern "C" void kernel_launch(void* const* d_in, const int* in_sizes, int n_in,
                              void* d_out, int out_size, void* d_ws, size_t ws_size,
                              hipStream_t stream){
  const float* x    = (const float*)d_in[0];
  const float* fb   = (const float*)d_in[1];
  const float* encw = (const float*)d_in[2];
  const float* encb = (const float*)d_in[3];
  const float* upw  = (const float*)d_in[4];
  const float* upb  = (const float*)d_in[5];
  const float* dnw  = (const float*)d_in[6];
  const float* dnb  = (const float*)d_in[7];
  const float* decw = (const float*)d_in[8];
  const float* decb = (const float*)d_in[9];
  float* out = (float*)d_out;
  char* ws = (char*)d_ws;

  size_t o = 0;
  float* bufA = (float*)(ws + o); o += (size_t)NB*NC*NT*4;
  float* bufB = (float*)(ws + o); o += (size_t)NB*NC*NT*4;
  u32*  keys  = (u32*)(ws + o);   o += (size_t)NB*NUP*1024*4;
  u32*  hist1 = (u32*)(ws + o);   o += 1024*NB*4;
  u32*  hist2 = (u32*)(ws + o);   o += 1024*NB*4;
  u32*  cstar = (u32*)(ws + o);   o += 64;
  u32*  nab   = (u32*)(ws + o);   o += 64;
  u32*  t0k   = (u32*)(ws + o);   o += 64;
  int*  cnt   = (int*)(ws + o);   o += 64;
  float* tv   = (float*)(ws + o); o += NB*64*4;
  int*  ti    = (int*)(ws + o);   o += NB*64*4;
  float* cval = (float*)(ws + o); o += (size_t)NB*CAP*4;
  int*  cidx  = (int*)(ws + o);   o += (size_t)NB*CAP*4;
  float* part = (float*)(ws + o); o += (size_t)16*NB*NT*4;
  u16*  wdil  = (u16*)(ws + o);   o += (size_t)12*65536*2;   // 1.57 MB
  u16*  wup   = (u16*)(ws + o);   o += (size_t)4*128*1024*2; // 1.05 MB

  static const int dil[6] = {1,3,9,27,81,1};

  k_init<<<dim3(16), dim3(256), 0, stream>>>(hist1, hist2, cnt);
  k_prep<<<dim3(320), dim3(256), 0, stream>>>(encw, decw, upw, wdil, wup);
  k_fb<<<dim3(256,2,NB), dim3(256), 0, stream>>>(x, fb, bufA);

  float* src = bufA; float* dst = bufB;
  for (int l=0;l<6;++l){
    k_dil<<<dim3(256,NB), dim3(256), 0, stream>>>(src, dst, wdil + (size_t)l*65536, encb + l*NC, dil[l], 0);
    float* t = src; src = dst; dst = t;
  }
  // encoder output in src == bufA

  k_sub<<<dim3(32,4,NB), dim3(256), 0, stream>>>(src, upw, upb, keys, hist1);
  k_sel<<<dim3(NB), dim3(256), 0, stream>>>(hist1, cstar, nab, t0k, 1);
  k_h2 <<<dim3(4096), dim3(256), 0, stream>>>(keys, cstar, hist2);
  k_sel<<<dim3(NB), dim3(256), 0, stream>>>(hist2, cstar, nab, t0k, 2);
  k_up <<<dim3(16,256,NB), dim3(256), 0, stream>>>(src, wup, upb, t0k, cval, cidx, cnt);
  k_top<<<dim3(NB), dim3(256), 0, stream>>>(cval, cidx, cnt, tv, ti);

  k_fill<<<dim3(NB*NC), dim3(256), 0, stream>>>(bufB, dnb);
  k_scat<<<dim3(NB,64), dim3(128), 0, stream>>>(bufB, dnw, tv, ti);

  src = bufB; dst = bufA;
  for (int l=0;l<6;++l){
    k_dil<<<dim3(256,NB), dim3(256), 0, stream>>>(src, dst, wdil + (size_t)(6+l)*65536, decb + l*NC, dil[l], 1);
    float* t = src; src = dst; dst = t;
  }
  // decoder output in src == bufB

  k_syn<<<dim3(8,16,NB), dim3(256), 0, stream>>>(src, fb, part);
  k_red<<<dim3(256), dim3(256), 0, stream>>>(part, out);
}

// Round 3
// 1147.044 us; speedup vs baseline: 2.2038x; 1.2121x over previous
//
#include <hip/hip_runtime.h>
#include <stdint.h>

#define NB  2
#define NC  128
#define NT  32768
#define KFB 512
#define NUP 2048
#define CAP 14336

typedef unsigned int u32;
typedef unsigned short u16;
typedef short s16;
typedef float f32x4 __attribute__((ext_vector_type(4)));
typedef s16 short8 __attribute__((ext_vector_type(8)));
typedef u32 u32x4 __attribute__((ext_vector_type(4)));

__device__ __forceinline__ u32 f2key(float v){
  u32 u = __float_as_uint(v);
  return (u & 0x80000000u) ? ~u : (u | 0x80000000u);
}
__device__ __forceinline__ float key2f(u32 k){
  u32 u = (k & 0x80000000u) ? (k & 0x7FFFFFFFu) : ~k;
  return __uint_as_float(u);
}
__device__ __forceinline__ u16 bf16rn(float v){
  u32 u = __float_as_uint(v);
  return (u16)((u + 0x7FFFu + ((u>>16)&1u)) >> 16);
}

// ============ K0: init (zero histograms + counters) ============
__global__ void k_init(u32* __restrict__ h1, u32* __restrict__ h2, int* __restrict__ counts){
  int i = blockIdx.x*256 + threadIdx.x;
  if (i < 2048) h1[i] = 0u;
  else if (i < 4096) h2[i-2048] = 0u;
  if (i < NB) counts[i] = 0;
}

// ============ K_prep: split weights to bf16 hi/lo in MFMA A-fragment order ============
// A[m][k] layout (16x16x32 bf16): m = lane&15, k = (lane>>4)*8 + j
// dil: [layer 12][s 8][mt 8] units; up: [s 4][umt 128]; fb: [s 16][mt 8]
__global__ __launch_bounds__(256) void k_prep(const float* __restrict__ encw,
    const float* __restrict__ decw, const float* __restrict__ upw,
    const float* __restrict__ fbw,
    u16* __restrict__ wdil, u16* __restrict__ wup, u16* __restrict__ wfb){
  int g = blockIdx.x*256 + threadIdx.x;
  if (g < 49152){
    int l = g & 63, mt = (g>>6)&7, s = (g>>9)&7, layer = g>>12;
    const float* W = (layer < 6) ? (encw + (size_t)layer*NC*NC*2)
                                 : (decw + (size_t)(layer-6)*NC*NC*2);
    int co = mt*16 + (l & 15);
    int kb = s*32 + ((l>>4)<<3);
    union { u16 h[8]; u32x4 q; } H, L;
    #pragma unroll
    for (int j=0;j<8;++j){
      int k = kb + j;
      float v = W[((size_t)co*NC + (k&127))*2 + (k>>7)];
      u16 h = bf16rn(v);
      H.h[j] = h;
      L.h[j] = bf16rn(v - __uint_as_float(((u32)h)<<16));
    }
    int unit = g >> 6;
    *(u32x4*)(wdil + (size_t)unit*1024 + (l<<3)) = H.q;
    *(u32x4*)(wdil + (size_t)unit*1024 + 512 + (l<<3)) = L.q;
  } else if (g < 81920){
    int g2 = g - 49152;
    int l = g2 & 63, umt = (g2>>6)&127, s = g2>>13;
    int u = umt*16 + (l & 15);
    int kb = s*32 + ((l>>4)<<3);
    union { u16 h[8]; u32x4 q; } H, L;
    #pragma unroll
    for (int j=0;j<8;++j){
      float v = upw[(size_t)u*NC + kb + j];
      u16 h = bf16rn(v);
      H.h[j] = h;
      L.h[j] = bf16rn(v - __uint_as_float(((u32)h)<<16));
    }
    int unit = g2 >> 6;
    *(u32x4*)(wup + (size_t)unit*1024 + (l<<3)) = H.q;
    *(u32x4*)(wup + (size_t)unit*1024 + 512 + (l<<3)) = L.q;
  } else if (g < 90112){
    int g3 = g - 81920;
    int l = g3 & 63, mt = (g3>>6)&7, s = g3>>9;
    int c = mt*16 + (l & 15);
    int kb = s*32 + ((l>>4)<<3);
    union { u16 h[8]; u32x4 q; } H, L;
    #pragma unroll
    for (int j=0;j<8;++j){
      float v = fbw[(size_t)c*KFB + kb + j];
      u16 h = bf16rn(v);
      H.h[j] = h;
      L.h[j] = bf16rn(v - __uint_as_float(((u32)h)<<16));
    }
    int unit = g3 >> 6;
    *(u32x4*)(wfb + (size_t)unit*1024 + (l<<3)) = H.q;
    *(u32x4*)(wfb + (size_t)unit*1024 + 512 + (l<<3)) = L.q;
  }
}

// ============ K1: filterbank analysis — bf16x3 MFMA ============
// spec[b,c,t] = sum_k fb[c,k] * x[b, t+k-256].  M=128 c, N=128 t, K=512.
// B[k][n] = xw[k+n] (Toeplitz window in LDS, packed hi/lo).
__global__ __launch_bounds__(256) void k_fb(const float* __restrict__ x,
    const u16* __restrict__ wfb, float* __restrict__ spec){
  __shared__ u32 xw[640];
  const int tid = threadIdx.x;
  const int t0 = blockIdx.x << 7;
  const int b  = blockIdx.y;
  const int lane = tid & 63, w = tid >> 6;
  const int wy = w >> 1, wx = w & 1;
  const int quad = lane >> 4, l15 = lane & 15;
  for (int i = tid; i < 640; i += 256){
    int t = t0 - 256 + i;
    float v = ((u32)t < (u32)NT) ? x[b*NT + t] : 0.0f;
    u16 h = bf16rn(v);
    u16 lo = bf16rn(v - __uint_as_float(((u32)h)<<16));
    xw[i] = ((u32)h<<16) | lo;
  }
  __syncthreads();
  f32x4 acc[4][4] = {};
  for (int s = 0; s < 16; ++s){
    short8 ah[4], al[4];
    #pragma unroll
    for (int mt=0; mt<4; ++mt){
      const u16* p = wfb + (size_t)(s*8 + wy*4 + mt)*1024 + (lane<<3);
      ah[mt] = *(const short8*)p;
      al[mt] = *(const short8*)(p + 512);
    }
    short8 xh[4], xl[4];
    #pragma unroll
    for (int nt=0; nt<4; ++nt){
      int base = s*32 + quad*8 + (wx<<6) + (nt<<4) + l15;
      u32 r[8];
      #pragma unroll
      for (int j=0;j<8;++j) r[j] = xw[base + j];
      union { u32 u[4]; short8 v; } H, L;
      H.u[0] = __builtin_amdgcn_perm(r[1], r[0], 0x07060302u);
      H.u[1] = __builtin_amdgcn_perm(r[3], r[2], 0x07060302u);
      H.u[2] = __builtin_amdgcn_perm(r[5], r[4], 0x07060302u);
      H.u[3] = __builtin_amdgcn_perm(r[7], r[6], 0x07060302u);
      L.u[0] = __builtin_amdgcn_perm(r[1], r[0], 0x05040100u);
      L.u[1] = __builtin_amdgcn_perm(r[3], r[2], 0x05040100u);
      L.u[2] = __builtin_amdgcn_perm(r[5], r[4], 0x05040100u);
      L.u[3] = __builtin_amdgcn_perm(r[7], r[6], 0x05040100u);
      xh[nt] = H.v; xl[nt] = L.v;
    }
    #pragma unroll
    for (int mt=0; mt<4; ++mt){
      #pragma unroll
      for (int nt=0; nt<4; ++nt){
        acc[mt][nt] = __builtin_amdgcn_mfma_f32_16x16x32_bf16(ah[mt], xh[nt], acc[mt][nt], 0,0,0);
        acc[mt][nt] = __builtin_amdgcn_mfma_f32_16x16x32_bf16(ah[mt], xl[nt], acc[mt][nt], 0,0,0);
        acc[mt][nt] = __builtin_amdgcn_mfma_f32_16x16x32_bf16(al[mt], xh[nt], acc[mt][nt], 0,0,0);
      }
    }
  }
  #pragma unroll
  for (int mt=0; mt<4; ++mt){
    #pragma unroll
    for (int r=0; r<4; ++r){
      const int c = (wy<<6) + (mt<<4) + (quad<<2) + r;
      float* po = spec + (size_t)(b*NC+c)*NT + t0 + (wx<<6) + l15;
      #pragma unroll
      for (int nt=0; nt<4; ++nt) po[nt<<4] = acc[mt][nt][r];
    }
  }
}

// ============ K2: dilated residual conv layer — bf16x3 MFMA ============
__global__ __launch_bounds__(256,2) void k_dil(const float* __restrict__ xin,
    float* __restrict__ xout, const u16* __restrict__ wf,
    const float* __restrict__ bias, int d, int mode){
  __shared__ u32 lx[212*32];
  const int tid = threadIdx.x;
  const int b  = blockIdx.y;
  const int t0 = blockIdx.x << 7;
  const int base = mode ? -d : 0;
  const int lane = tid & 63, w = tid >> 6;
  const int wy = w >> 1, wx = w & 1;
  const int quad = lane >> 4, l15 = lane & 15;
  const int ci_l = tid >> 3, sub = tid & 7;
  f32x4 acc[4][4] = {};
  const float* xb = xin + (size_t)b*NC*NT;
  for (int cc = 0; cc < 4; ++cc){
    __syncthreads();
    const float* xr = xb + (size_t)(cc*32 + ci_l)*NT;
    #pragma unroll
    for (int j=0;j<27;++j){
      int tl = sub + (j<<3);
      if (tl < 212){
        int tg = t0 + base + tl;
        float v = ((u32)tg < (u32)NT) ? xr[tg] : 0.0f;
        u16 h = bf16rn(v);
        u16 lo = bf16rn(v - __uint_as_float(((u32)h)<<16));
        lx[(tl<<5) + (ci_l ^ ((tl&3)<<3))] = ((u32)h<<16) | lo;
      }
    }
    __syncthreads();
    #pragma unroll
    for (int tap = 0; tap < 2; ++tap){
      const int off = tap ? d : 0;
      const int s = (tap<<2) + cc;
      short8 ah[4], al[4];
      #pragma unroll
      for (int mt=0; mt<4; ++mt){
        const u16* p = wf + (size_t)(s*8 + wy*4 + mt)*1024 + (lane<<3);
        ah[mt] = *(const short8*)p;
        al[mt] = *(const short8*)(p + 512);
      }
      short8 xh[4], xl[4];
      #pragma unroll
      for (int nt=0; nt<4; ++nt){
        int T = off + (wx<<6) + (nt<<4) + l15;
        int idx = (T<<5) + ((quad<<3) ^ ((T&3)<<3));
        u32x4 r0 = *(const u32x4*)&lx[idx];
        u32x4 r1 = *(const u32x4*)&lx[idx+4];
        union { u32 u[4]; short8 v; } H, L;
        H.u[0] = __builtin_amdgcn_perm(r0.y, r0.x, 0x07060302u);
        H.u[1] = __builtin_amdgcn_perm(r0.w, r0.z, 0x07060302u);
        H.u[2] = __builtin_amdgcn_perm(r1.y, r1.x, 0x07060302u);
        H.u[3] = __builtin_amdgcn_perm(r1.w, r1.z, 0x07060302u);
        L.u[0] = __builtin_amdgcn_perm(r0.y, r0.x, 0x05040100u);
        L.u[1] = __builtin_amdgcn_perm(r0.w, r0.z, 0x05040100u);
        L.u[2] = __builtin_amdgcn_perm(r1.y, r1.x, 0x05040100u);
        L.u[3] = __builtin_amdgcn_perm(r1.w, r1.z, 0x05040100u);
        xh[nt] = H.v; xl[nt] = L.v;
      }
      #pragma unroll
      for (int mt=0; mt<4; ++mt){
        #pragma unroll
        for (int nt=0; nt<4; ++nt){
          acc[mt][nt] = __builtin_amdgcn_mfma_f32_16x16x32_bf16(ah[mt], xh[nt], acc[mt][nt], 0,0,0);
          acc[mt][nt] = __builtin_amdgcn_mfma_f32_16x16x32_bf16(ah[mt], xl[nt], acc[mt][nt], 0,0,0);
          acc[mt][nt] = __builtin_amdgcn_mfma_f32_16x16x32_bf16(al[mt], xh[nt], acc[mt][nt], 0,0,0);
        }
      }
    }
  }
  #pragma unroll
  for (int mt=0; mt<4; ++mt){
    #pragma unroll
    for (int r=0; r<4; ++r){
      const int co = (wy<<6) + (mt<<4) + (quad<<2) + r;
      const float bv = bias[co];
      const float* xi = xb + (size_t)co*NT + t0 + (wx<<6) + l15;
      float* xo = xout + (size_t)(b*NC+co)*NT + t0 + (wx<<6) + l15;
      #pragma unroll
      for (int nt=0; nt<4; ++nt){
        float h = acc[mt][nt][r] + bv;
        h = (h >= 0.f) ? h : 0.2f*h;
        xo[nt<<4] = xi[nt<<4] + h;
      }
    }
  }
}

// ============ K3a: up-proj on t-subsample (fp32, keys + coarse hist) ============
__global__ __launch_bounds__(256) void k_sub(const float* __restrict__ enc,
                                             const float* __restrict__ upw,
                                             const float* __restrict__ upb,
                                             u32* __restrict__ keys,
                                             u32* __restrict__ hist1){
  const int u0 = blockIdx.x * 64;
  const int i0 = blockIdx.y * 256;
  const int b  = blockIdx.z;
  __shared__ float uwl[32][68];
  __shared__ float ec[32][260];
  __shared__ u32 lh[1024];
  const int tid = threadIdx.x;
  for (int i=tid;i<1024;i+=256) lh[i] = 0u;
  const int ug = tid & 15;
  const int ig = tid >> 4;
  float acc[4][16];
  #pragma unroll
  for (int i=0;i<4;++i){
    #pragma unroll
    for (int j=0;j<16;++j) acc[i][j]=0.0f;
  }
  for (int c0=0;c0<NC;c0+=32){
    __syncthreads();
    #pragma unroll
    for (int i=0;i<8;++i){
      int flat = i*256+tid;
      uwl[flat & 31][flat >> 5] = upw[(size_t)(u0 + (flat>>5))*NC + c0 + (flat&31)];
    }
    #pragma unroll
    for (int i=0;i<32;++i){
      int flat = i*256+tid;
      ec[flat >> 8][flat & 255] = enc[(size_t)(b*NC + c0 + (flat>>8))*NT + (size_t)(i0 + (flat&255))*32];
    }
    __syncthreads();
    #pragma unroll 2
    for (int cc=0;cc<32;++cc){
      float a[4], bb[16];
      *(float4*)&a[0] = *(const float4*)&uwl[cc][ug*4];
      #pragma unroll
      for (int m=0;m<4;++m)
        *(float4*)&bb[m*4] = *(const float4*)&ec[cc][ig*16 + m*4];
      #pragma unroll
      for (int i=0;i<4;++i){
        #pragma unroll
        for (int j=0;j<16;++j)
          acc[i][j] = fmaf(a[i], bb[j], acc[i][j]);
      }
    }
  }
  #pragma unroll
  for (int i=0;i<4;++i){
    int u = u0 + ug*4 + i;
    float ub = upb[u];
    #pragma unroll
    for (int j=0;j<16;++j){
      float v = acc[i][j] + ub;
      u32 k = f2key(v);
      keys[(size_t)(b*NUP + u)*1024 + i0 + ig*16 + j] = k;
      atomicAdd(&lh[k >> 22], 1u);
    }
  }
  __syncthreads();
  for (int i=tid;i<1024;i+=256){
    u32 c = lh[i];
    if (c) atomicAdd(&hist1[b*1024 + i], c);
  }
}

// ============ K3sel: suffix-scan histogram, pick rank-64 bin ============
__global__ __launch_bounds__(256) void k_sel(const u32* __restrict__ hist,
                                             u32* __restrict__ cstar,
                                             u32* __restrict__ nab,
                                             u32* __restrict__ t0key,
                                             int phase){
  const int b = blockIdx.x;
  __shared__ u32 s1[1024];
  __shared__ u32 s2[1024];
  __shared__ int red[256];
  const int tid = threadIdx.x;
  for (int i=tid;i<1024;i+=256) s1[i] = hist[b*1024 + i];
  __syncthreads();
  u32* cur = s1; u32* nxt = s2;
  for (int off=1; off<1024; off<<=1){
    for (int i=tid;i<1024;i+=256){
      u32 v = cur[i];
      if (i + off < 1024) v += cur[i+off];
      nxt[i] = v;
    }
    __syncthreads();
    u32* t = cur; cur = nxt; nxt = t;
  }
  u32 off0 = (phase==1) ? 0u : nab[b];
  int best = -1;
  for (int i=tid;i<1024;i+=256)
    if (off0 + cur[i] >= 64u && i > best) best = i;
  red[tid] = best;
  __syncthreads();
  for (int st=128; st>0; st>>=1){
    if (tid < st) red[tid] = max(red[tid], red[tid+st]);
    __syncthreads();
  }
  if (tid == 0){
    int bi = (red[0] < 0) ? 0 : red[0];
    if (phase == 1){
      cstar[b] = (u32)bi;
      nab[b] = (bi < 1023) ? cur[bi+1] : 0u;
    } else {
      t0key[b] = (cstar[b] << 22) | (((u32)bi) << 12);
    }
  }
}

// ============ K3h2: fine histogram within coarse bin ============
__global__ void k_h2(const u32* __restrict__ keys, const u32* __restrict__ cstar,
                     u32* __restrict__ hist2){
  const u32 c0 = cstar[0], c1 = cstar[1];
  int i = blockIdx.x*256 + threadIdx.x;
  const int total = NB*NUP*1024;
  const int stride = gridDim.x*256;
  for (; i < total; i += stride){
    u32 k = keys[i];
    u32 cs = (i >> 21) ? c1 : c0;
    if ((k >> 22) == cs) atomicAdd(&hist2[((u32)(i>>21)<<10) + ((k>>12) & 1023u)], 1u);
  }
}

// ============ K3b: full up-proj — bf16x3 MFMA, append candidates >= threshold ============
__global__ __launch_bounds__(256,2) void k_up(const float* __restrict__ enc,
    const u16* __restrict__ wf, const float* __restrict__ upb,
    const u32* __restrict__ t0key, float* __restrict__ cval,
    int* __restrict__ cidx, int* __restrict__ counts){
  __shared__ u32 lx[128*32];
  const int tid = threadIdx.x;
  const int u0 = blockIdx.x << 7;
  const int t0 = blockIdx.y << 7;
  const int b  = blockIdx.z;
  const int lane = tid & 63, w = tid >> 6;
  const int wy = w >> 1, wx = w & 1;
  const int quad = lane >> 4, l15 = lane & 15;
  const int ci_l = tid >> 3, sub = tid & 7;
  f32x4 acc[4][4] = {};
  for (int cc = 0; cc < 4; ++cc){
    __syncthreads();
    const float* xr = enc + (size_t)(b*NC + cc*32 + ci_l)*NT + t0;
    #pragma unroll
    for (int j=0;j<16;++j){
      int tl = sub + (j<<3);
      float v = xr[tl];
      u16 h = bf16rn(v);
      u16 lo = bf16rn(v - __uint_as_float(((u32)h)<<16));
      lx[(tl<<5) + (ci_l ^ ((tl&3)<<3))] = ((u32)h<<16) | lo;
    }
    __syncthreads();
    short8 ah[4], al[4];
    #pragma unroll
    for (int mt=0; mt<4; ++mt){
      const u16* p = wf + (size_t)(cc*128 + (u0>>4) + wy*4 + mt)*1024 + (lane<<3);
      ah[mt] = *(const short8*)p;
      al[mt] = *(const short8*)(p + 512);
    }
    short8 xh[4], xl[4];
    #pragma unroll
    for (int nt=0; nt<4; ++nt){
      int T = (wx<<6) + (nt<<4) + l15;
      int idx = (T<<5) + ((quad<<3) ^ ((T&3)<<3));
      u32x4 r0 = *(const u32x4*)&lx[idx];
      u32x4 r1 = *(const u32x4*)&lx[idx+4];
      union { u32 u[4]; short8 v; } H, L;
      H.u[0] = __builtin_amdgcn_perm(r0.y, r0.x, 0x07060302u);
      H.u[1] = __builtin_amdgcn_perm(r0.w, r0.z, 0x07060302u);
      H.u[2] = __builtin_amdgcn_perm(r1.y, r1.x, 0x07060302u);
      H.u[3] = __builtin_amdgcn_perm(r1.w, r1.z, 0x07060302u);
      L.u[0] = __builtin_amdgcn_perm(r0.y, r0.x, 0x05040100u);
      L.u[1] = __builtin_amdgcn_perm(r0.w, r0.z, 0x05040100u);
      L.u[2] = __builtin_amdgcn_perm(r1.y, r1.x, 0x05040100u);
      L.u[3] = __builtin_amdgcn_perm(r1.w, r1.z, 0x05040100u);
      xh[nt] = H.v; xl[nt] = L.v;
    }
    #pragma unroll
    for (int mt=0; mt<4; ++mt){
      #pragma unroll
      for (int nt=0; nt<4; ++nt){
        acc[mt][nt] = __builtin_amdgcn_mfma_f32_16x16x32_bf16(ah[mt], xh[nt], acc[mt][nt], 0,0,0);
        acc[mt][nt] = __builtin_amdgcn_mfma_f32_16x16x32_bf16(ah[mt], xl[nt], acc[mt][nt], 0,0,0);
        acc[mt][nt] = __builtin_amdgcn_mfma_f32_16x16x32_bf16(al[mt], xh[nt], acc[mt][nt], 0,0,0);
      }
    }
  }
  float T0 = key2f(t0key[b]);
  T0 -= fabsf(T0)*3e-4f + 1e-5f;
  #pragma unroll
  for (int mt=0; mt<4; ++mt){
    #pragma unroll
    for (int r=0; r<4; ++r){
      int u = u0 + (wy<<6) + (mt<<4) + (quad<<2) + r;
      float ub = upb[u];
      #pragma unroll
      for (int nt=0; nt<4; ++nt){
        float v = acc[mt][nt][r] + ub;
        if (v >= T0){
          int slot = atomicAdd(&counts[b], 1);
          if (slot < CAP){
            cval[b*CAP + slot] = v;
            cidx[b*CAP + slot] = u*NT + (t0 + (wx<<6) + (nt<<4) + l15);
          }
        }
      }
    }
  }
}

// ============ K3c: exact top-64 of candidates ============
__global__ __launch_bounds__(256) void k_top(const float* __restrict__ cval,
                                             const int* __restrict__ cidx,
                                             const int* __restrict__ counts,
                                             float* __restrict__ tv,
                                             int* __restrict__ ti){
  const int b = blockIdx.x;
  __shared__ float lv[CAP];
  __shared__ float sv[256];
  __shared__ int   si[256];
  const int tid = threadIdx.x;
  int n = counts[b]; if (n > CAP) n = CAP;
  for (int i=tid;i<n;i+=256) lv[i] = cval[b*CAP+i];
  __syncthreads();
  for (int r=0;r<64;++r){
    float best = -3.4e38f; int bi = -1;
    for (int i=tid;i<n;i+=256){
      float v = lv[i];
      if (v > best){ best = v; bi = i; }
    }
    sv[tid]=best; si[tid]=bi;
    __syncthreads();
    for (int st=128; st>0; st>>=1){
      if (tid < st && sv[tid+st] > sv[tid]){ sv[tid]=sv[tid+st]; si[tid]=si[tid+st]; }
      __syncthreads();
    }
    if (tid == 0){
      int kb = si[0];
      if (kb >= 0){
        tv[b*64+r] = sv[0];
        ti[b*64+r] = cidx[b*CAP+kb];
        lv[kb] = -3.4e38f;
      } else { tv[b*64+r] = 0.0f; ti[b*64+r] = 0; }
    }
    __syncthreads();
  }
}

// ============ K4a: fill decoder input with down_b ============
__global__ void k_fill(float* __restrict__ dst, const float* __restrict__ downb){
  const int bc = blockIdx.x;
  const int c = bc & 127;
  float v = downb[c];
  float4 vv; vv.x=v; vv.y=v; vv.z=v; vv.w=v;
  float4* p = (float4*)(dst + (size_t)bc*NT);
  for (int i=threadIdx.x; i < NT/4; i += 256) p[i] = vv;
}

// ============ K4b: scatter spikes through down_w ============
__global__ void k_scat(float* __restrict__ dst, const float* __restrict__ downw,
                       const float* __restrict__ tv, const int* __restrict__ ti){
  const int b = blockIdx.x, r = blockIdx.y;
  float v = tv[b*64+r];
  int idx = ti[b*64+r];
  int u = idx / NT, t = idx - u*NT;
  int c = threadIdx.x;
  atomicAdd(&dst[(size_t)(b*NC+c)*NT + t], downw[(size_t)c*NUP + u] * v);
}

// ============ K6: transposed filterbank synthesis (fp32, conflict-free LDS) ============
// win stored transposed: win2[i%16][i/16], row stride 289 (289 % 32 == 1).
// Register-shift loop reads row=const, col=tid+const -> lane stride 1 -> no conflicts.
#define TS 4096
__global__ __launch_bounds__(256) void k_syn(const float* __restrict__ dec,
                                             const float* __restrict__ fb,
                                             float* __restrict__ part){
  const int ts = blockIdx.x;
  const int cs = blockIdx.y;
  const int b  = blockIdx.z;
  const int t0 = ts * TS;
  __shared__ float win2[16*289 + 8];
  __shared__ float fbl[512];
  const int tid = threadIdx.x;
  const int tl = tid * 16;
  float acc[16];
  #pragma unroll
  for (int j=0;j<16;++j) acc[j] = 0.0f;
  for (int c = cs*8; c < cs*8+8; ++c){
    __syncthreads();
    for (int i=tid; i < TS+511; i += 256){
      int t = t0 - 255 + i;
      win2[(i & 15)*289 + (i >> 4)] = ((u32)t < (u32)NT) ? dec[(size_t)(b*NC+c)*NT + t] : 0.0f;
    }
    for (int i=tid; i<512; i+=256) fbl[i] = fb[c*KFB + i];
    __syncthreads();
    float w[23];
    #pragma unroll
    for (int k=0;k<23;++k){
      int i = tl + 504 + k;
      w[k] = win2[(i & 15)*289 + (i >> 4)];
    }
    for (int G=0; G<64; ++G){
      float4 f0 = *(const float4*)&fbl[G*8];
      float4 f1 = *(const float4*)&fbl[G*8+4];
      float fq[8] = {f0.x, f0.y, f0.z, f0.w, f1.x, f1.y, f1.z, f1.w};
      #pragma unroll
      for (int q=0;q<8;++q){
        #pragma unroll
        for (int jj=0;jj<16;++jj)
          acc[jj] = fmaf(fq[q], w[7-q+jj], acc[jj]);
      }
      if (G != 63){
        #pragma unroll
        for (int k=22;k>=8;--k) w[k] = w[k-8];
        #pragma unroll
        for (int k=0;k<8;++k){
          int i = tl + 496 - 8*G + k;
          w[k] = win2[(i & 15)*289 + (i >> 4)];
        }
      }
    }
  }
  float* po = &part[(size_t)(cs*NB + b)*NT + t0 + tl];
  #pragma unroll
  for (int m=0;m<4;++m){
    float4 ov; ov.x=acc[m*4+0]; ov.y=acc[m*4+1]; ov.z=acc[m*4+2]; ov.w=acc[m*4+3];
    *(float4*)&po[m*4] = ov;
  }
}

// ============ K6r: reduce partials -> out ============
__global__ void k_red(const float* __restrict__ part, float* __restrict__ out){
  int i = blockIdx.x*256 + threadIdx.x;
  float s = 0.0f;
  #pragma unroll
  for (int cs=0;cs<16;++cs) s += part[(size_t)cs*(NB*NT) + i];
  out[i] = s;
}

extern "C" void kernel_launch(void* const* d_in, const int* in_sizes, int n_in,
                              void* d_out, int out_size, void* d_ws, size_t ws_size,
                              hipStream_t stream){
  const float* x    = (const float*)d_in[0];
  const float* fb   = (const float*)d_in[1];
  const float* encw = (const float*)d_in[2];
  const float* encb = (const float*)d_in[3];
  const float* upw  = (const float*)d_in[4];
  const float* upb  = (const float*)d_in[5];
  const float* dnw  = (const float*)d_in[6];
  const float* dnb  = (const float*)d_in[7];
  const float* decw = (const float*)d_in[8];
  const float* decb = (const float*)d_in[9];
  float* out = (float*)d_out;
  char* ws = (char*)d_ws;

  size_t o = 0;
  float* bufA = (float*)(ws + o); o += (size_t)NB*NC*NT*4;
  float* bufB = (float*)(ws + o); o += (size_t)NB*NC*NT*4;
  u32*  keys  = (u32*)(ws + o);   o += (size_t)NB*NUP*1024*4;
  u32*  hist1 = (u32*)(ws + o);   o += 1024*NB*4;
  u32*  hist2 = (u32*)(ws + o);   o += 1024*NB*4;
  u32*  cstar = (u32*)(ws + o);   o += 64;
  u32*  nab   = (u32*)(ws + o);   o += 64;
  u32*  t0k   = (u32*)(ws + o);   o += 64;
  int*  cnt   = (int*)(ws + o);   o += 64;
  float* tv   = (float*)(ws + o); o += NB*64*4;
  int*  ti    = (int*)(ws + o);   o += NB*64*4;
  float* cval = (float*)(ws + o); o += (size_t)NB*CAP*4;
  int*  cidx  = (int*)(ws + o);   o += (size_t)NB*CAP*4;
  float* part = (float*)(ws + o); o += (size_t)16*NB*NT*4;
  u16*  wdil  = (u16*)(ws + o);   o += (size_t)12*65536*2;   // 1.57 MB
  u16*  wup   = (u16*)(ws + o);   o += (size_t)4*128*1024*2; // 1.05 MB
  u16*  wfb   = (u16*)(ws + o);   o += (size_t)128*1024*2;   // 0.26 MB

  static const int dil[6] = {1,3,9,27,81,1};

  k_init<<<dim3(16), dim3(256), 0, stream>>>(hist1, hist2, cnt);
  k_prep<<<dim3(352), dim3(256), 0, stream>>>(encw, decw, upw, fb, wdil, wup, wfb);
  k_fb<<<dim3(256,NB), dim3(256), 0, stream>>>(x, wfb, bufA);

  float* src = bufA; float* dst = bufB;
  for (int l=0;l<6;++l){
    k_dil<<<dim3(256,NB), dim3(256), 0, stream>>>(src, dst, wdil + (size_t)l*65536, encb + l*NC, dil[l], 0);
    float* t = src; src = dst; dst = t;
  }
  // encoder output in src == bufA

  k_sub<<<dim3(32,4,NB), dim3(256), 0, stream>>>(src, upw, upb, keys, hist1);
  k_sel<<<dim3(NB), dim3(256), 0, stream>>>(hist1, cstar, nab, t0k, 1);
  k_h2 <<<dim3(4096), dim3(256), 0, stream>>>(keys, cstar, hist2);
  k_sel<<<dim3(NB), dim3(256), 0, stream>>>(hist2, cstar, nab, t0k, 2);
  k_up <<<dim3(16,256,NB), dim3(256), 0, stream>>>(src, wup, upb, t0k, cval, cidx, cnt);
  k_top<<<dim3(NB), dim3(256), 0, stream>>>(cval, cidx, cnt, tv, ti);

  k_fill<<<dim3(NB*NC), dim3(256), 0, stream>>>(bufB, dnb);
  k_scat<<<dim3(NB,64), dim3(128), 0, stream>>>(bufB, dnw, tv, ti);

  src = bufB; dst = bufA;
  for (int l=0;l<6;++l){
    k_dil<<<dim3(256,NB), dim3(256), 0, stream>>>(src, dst, wdil + (size_t)(6+l)*65536, decb + l*NC, dil[l], 1);
    float* t = src; src = dst; dst = t;
  }
  // decoder output in src == bufB

  k_syn<<<dim3(8,16,NB), dim3(256), 0, stream>>>(src, fb, part);
  k_red<<<dim3(256), dim3(256), 0, stream>>>(part, out);
}

// Round 4
// 1114.932 us; speedup vs baseline: 2.2673x; 1.0288x over previous
//
#include <hip/hip_runtime.h>
#include <stdint.h>

#define NB  2
#define NC  128
#define NT  32768
#define KFB 512
#define NUP 2048
#define CAP 14336

typedef unsigned int u32;
typedef unsigned short u16;
typedef short s16;
typedef float f32x4 __attribute__((ext_vector_type(4)));
typedef s16 short8 __attribute__((ext_vector_type(8)));
typedef u32 u32x4 __attribute__((ext_vector_type(4)));

__device__ __forceinline__ u32 f2key(float v){
  u32 u = __float_as_uint(v);
  return (u & 0x80000000u) ? ~u : (u | 0x80000000u);
}
__device__ __forceinline__ float key2f(u32 k){
  u32 u = (k & 0x80000000u) ? (k & 0x7FFFFFFFu) : ~k;
  return __uint_as_float(u);
}
__device__ __forceinline__ u16 bf16rn(float v){
  u32 u = __float_as_uint(v);
  return (u16)((u + 0x7FFFu + ((u>>16)&1u)) >> 16);
}
__device__ __forceinline__ void unpack8(const u32* p, short8& xh, short8& xl){
  u32x4 r0 = *(const u32x4*)p;
  u32x4 r1 = *(const u32x4*)(p + 4);
  union { u32 u[4]; short8 v; } H, L;
  H.u[0] = __builtin_amdgcn_perm(r0.y, r0.x, 0x07060302u);
  H.u[1] = __builtin_amdgcn_perm(r0.w, r0.z, 0x07060302u);
  H.u[2] = __builtin_amdgcn_perm(r1.y, r1.x, 0x07060302u);
  H.u[3] = __builtin_amdgcn_perm(r1.w, r1.z, 0x07060302u);
  L.u[0] = __builtin_amdgcn_perm(r0.y, r0.x, 0x05040100u);
  L.u[1] = __builtin_amdgcn_perm(r0.w, r0.z, 0x05040100u);
  L.u[2] = __builtin_amdgcn_perm(r1.y, r1.x, 0x05040100u);
  L.u[3] = __builtin_amdgcn_perm(r1.w, r1.z, 0x05040100u);
  xh = H.v; xl = L.v;
}

// ============ K0: init ============
__global__ void k_init(u32* __restrict__ h1, u32* __restrict__ h2, int* __restrict__ counts){
  int i = blockIdx.x*256 + threadIdx.x;
  if (i < 2048) h1[i] = 0u;
  else if (i < 4096) h2[i-2048] = 0u;
  if (i < NB) counts[i] = 0;
}

// ============ K_prep: split weights to bf16 hi/lo in MFMA A-fragment order ============
__global__ __launch_bounds__(256) void k_prep(const float* __restrict__ encw,
    const float* __restrict__ decw, const float* __restrict__ upw,
    const float* __restrict__ fbw,
    u16* __restrict__ wdil, u16* __restrict__ wup, u16* __restrict__ wfb){
  int g = blockIdx.x*256 + threadIdx.x;
  if (g < 49152){
    int l = g & 63, mt = (g>>6)&7, s = (g>>9)&7, layer = g>>12;
    const float* W = (layer < 6) ? (encw + (size_t)layer*NC*NC*2)
                                 : (decw + (size_t)(layer-6)*NC*NC*2);
    int co = mt*16 + (l & 15);
    int kb = s*32 + ((l>>4)<<3);
    union { u16 h[8]; u32x4 q; } H, L;
    #pragma unroll
    for (int j=0;j<8;++j){
      int k = kb + j;
      float v = W[((size_t)co*NC + (k&127))*2 + (k>>7)];
      u16 h = bf16rn(v);
      H.h[j] = h;
      L.h[j] = bf16rn(v - __uint_as_float(((u32)h)<<16));
    }
    int unit = g >> 6;
    *(u32x4*)(wdil + (size_t)unit*1024 + (l<<3)) = H.q;
    *(u32x4*)(wdil + (size_t)unit*1024 + 512 + (l<<3)) = L.q;
  } else if (g < 81920){
    int g2 = g - 49152;
    int l = g2 & 63, umt = (g2>>6)&127, s = g2>>13;
    int u = umt*16 + (l & 15);
    int kb = s*32 + ((l>>4)<<3);
    union { u16 h[8]; u32x4 q; } H, L;
    #pragma unroll
    for (int j=0;j<8;++j){
      float v = upw[(size_t)u*NC + kb + j];
      u16 h = bf16rn(v);
      H.h[j] = h;
      L.h[j] = bf16rn(v - __uint_as_float(((u32)h)<<16));
    }
    int unit = g2 >> 6;
    *(u32x4*)(wup + (size_t)unit*1024 + (l<<3)) = H.q;
    *(u32x4*)(wup + (size_t)unit*1024 + 512 + (l<<3)) = L.q;
  } else if (g < 90112){
    int g3 = g - 81920;
    int l = g3 & 63, mt = (g3>>6)&7, s = g3>>9;
    int c = mt*16 + (l & 15);
    int kb = s*32 + ((l>>4)<<3);
    union { u16 h[8]; u32x4 q; } H, L;
    #pragma unroll
    for (int j=0;j<8;++j){
      float v = fbw[(size_t)c*KFB + kb + j];
      u16 h = bf16rn(v);
      H.h[j] = h;
      L.h[j] = bf16rn(v - __uint_as_float(((u32)h)<<16));
    }
    int unit = g3 >> 6;
    *(u32x4*)(wfb + (size_t)unit*1024 + (l<<3)) = H.q;
    *(u32x4*)(wfb + (size_t)unit*1024 + 512 + (l<<3)) = L.q;
  }
}

// ============ K1: filterbank analysis — bf16x3 MFMA ============
__global__ __launch_bounds__(256) void k_fb(const float* __restrict__ x,
    const u16* __restrict__ wfb, float* __restrict__ spec){
  __shared__ u32 xw[640];
  const int tid = threadIdx.x;
  const int t0 = blockIdx.x << 7;
  const int b  = blockIdx.y;
  const int lane = tid & 63, w = tid >> 6;
  const int wy = w >> 1, wx = w & 1;
  const int quad = lane >> 4, l15 = lane & 15;
  for (int i = tid; i < 640; i += 256){
    int t = t0 - 256 + i;
    float v = ((u32)t < (u32)NT) ? x[b*NT + t] : 0.0f;
    u16 h = bf16rn(v);
    u16 lo = bf16rn(v - __uint_as_float(((u32)h)<<16));
    xw[i] = ((u32)h<<16) | lo;
  }
  __syncthreads();
  f32x4 acc[4][4] = {};
  for (int s = 0; s < 16; ++s){
    short8 ah[4], al[4];
    #pragma unroll
    for (int mt=0; mt<4; ++mt){
      const u16* p = wfb + (size_t)(s*8 + wy*4 + mt)*1024 + (lane<<3);
      ah[mt] = *(const short8*)p;
      al[mt] = *(const short8*)(p + 512);
    }
    short8 xh[4], xl[4];
    #pragma unroll
    for (int nt=0; nt<4; ++nt){
      int base = s*32 + quad*8 + (wx<<6) + (nt<<4) + l15;
      u32 r[8];
      #pragma unroll
      for (int j=0;j<8;++j) r[j] = xw[base + j];
      union { u32 u[4]; short8 v; } H, L;
      H.u[0] = __builtin_amdgcn_perm(r[1], r[0], 0x07060302u);
      H.u[1] = __builtin_amdgcn_perm(r[3], r[2], 0x07060302u);
      H.u[2] = __builtin_amdgcn_perm(r[5], r[4], 0x07060302u);
      H.u[3] = __builtin_amdgcn_perm(r[7], r[6], 0x07060302u);
      L.u[0] = __builtin_amdgcn_perm(r[1], r[0], 0x05040100u);
      L.u[1] = __builtin_amdgcn_perm(r[3], r[2], 0x05040100u);
      L.u[2] = __builtin_amdgcn_perm(r[5], r[4], 0x05040100u);
      L.u[3] = __builtin_amdgcn_perm(r[7], r[6], 0x05040100u);
      xh[nt] = H.v; xl[nt] = L.v;
    }
    #pragma unroll
    for (int mt=0; mt<4; ++mt){
      #pragma unroll
      for (int nt=0; nt<4; ++nt){
        acc[mt][nt] = __builtin_amdgcn_mfma_f32_16x16x32_bf16(ah[mt], xh[nt], acc[mt][nt], 0,0,0);
        acc[mt][nt] = __builtin_amdgcn_mfma_f32_16x16x32_bf16(ah[mt], xl[nt], acc[mt][nt], 0,0,0);
        acc[mt][nt] = __builtin_amdgcn_mfma_f32_16x16x32_bf16(al[mt], xh[nt], acc[mt][nt], 0,0,0);
      }
    }
  }
  #pragma unroll
  for (int mt=0; mt<4; ++mt){
    #pragma unroll
    for (int r=0; r<4; ++r){
      const int c = (wy<<6) + (mt<<4) + (quad<<2) + r;
      float* po = spec + (size_t)(b*NC+c)*NT + t0 + (wx<<6) + l15;
      #pragma unroll
      for (int nt=0; nt<4; ++nt) po[nt<<4] = acc[mt][nt][r];
    }
  }
}

// ============ K2: fused 6-layer dilated residual stack — bf16x3 MFMA, all-LDS ============
// mode 0 (enc, pad-right): h[t] = W0 x[t] + W1 x[t+d];  halo on RIGHT (122)
// mode 1 (dec, pad-left) : h[t] = W0 x[t-d] + W1 x[t];  halo on LEFT  (122)
// LDS x-buffer: 256 rows (t) x 128 ci, packed (hi<<16|lo) u32, 128 KB dynamic.
// All MFMA reads complete into acc before the write phase -> in-place safe.
// Garbage rows never propagate into valid rows (reads stay in prior valid window).
__global__ __launch_bounds__(256,1) void k_stack(const float* __restrict__ xin,
    float* __restrict__ xout, const u16* __restrict__ wf,
    const float* __restrict__ biases, int mode){
  extern __shared__ u32 lx[];           // [row 256][ci 128] with XOR swizzle
  const int tid = threadIdx.x;
  const int b  = blockIdx.y;
  const int T0 = blockIdx.x << 7;
  const int row0g = mode ? (T0 - 122) : T0;   // global t of LDS row 0
  const int lane = tid & 63, w = tid >> 6;
  const int wm = w >> 1, wn = w & 1;          // co-half, t-half
  const int quad = lane >> 4, l15 = lane & 15;
  // ---- stage-in: all 256 rows x 128 ci (OOB t -> 0)
  {
    const float* xb = xin + (size_t)b*NC*NT;
    const int rrow = tid;
    const int sw = (rrow & 3) << 3;
    const int tg = row0g + rrow;
    const bool ok = ((u32)tg < (u32)NT);
    for (int ci = 0; ci < NC; ++ci){
      float v = ok ? xb[(size_t)ci*NT + tg] : 0.0f;
      u16 h = bf16rn(v);
      u16 lo = bf16rn(v - __uint_as_float(((u32)h)<<16));
      lx[(rrow<<7) + (ci ^ sw)] = ((u32)h<<16) | lo;
    }
  }
  const int dils[6] = {1,3,9,27,81,1};
  for (int l = 0; l < 6; ++l){
    const int d = dils[l];
    const int o0 = mode ? -d : 0;
    const int o1 = mode ? 0 : d;
    const u16* wl = wf + ((size_t)l << 16);
    __syncthreads();
    f32x4 acc[4][8];
    #pragma unroll
    for (int mt=0;mt<4;++mt)
      #pragma unroll
      for (int nt=0;nt<8;++nt) acc[mt][nt] = (f32x4){0.f,0.f,0.f,0.f};
    for (int s = 0; s < 8; ++s){
      short8 ah[4], al[4];
      #pragma unroll
      for (int mt=0;mt<4;++mt){
        const u16* p = wl + (size_t)(((s<<3) + (wm<<2) + mt) << 10) + (lane<<3);
        ah[mt] = *(const short8*)p;
        al[mt] = *(const short8*)(p + 512);
      }
      const int o = (s >= 4) ? o1 : o0;
      const int cig = (s & 3) << 5;
      #pragma unroll
      for (int nt=0;nt<8;++nt){
        const int T = ((wn<<7) + (nt<<4) + l15 + o) & 255;
        const int idx = (T<<7) + cig + ((quad<<3) ^ ((T&3)<<3));
        short8 xh, xl;
        unpack8(&lx[idx], xh, xl);
        #pragma unroll
        for (int mt=0;mt<4;++mt){
          acc[mt][nt] = __builtin_amdgcn_mfma_f32_16x16x32_bf16(ah[mt], xh, acc[mt][nt], 0,0,0);
          acc[mt][nt] = __builtin_amdgcn_mfma_f32_16x16x32_bf16(ah[mt], xl, acc[mt][nt], 0,0,0);
          acc[mt][nt] = __builtin_amdgcn_mfma_f32_16x16x32_bf16(al[mt], xh, acc[mt][nt], 0,0,0);
        }
      }
    }
    __syncthreads();
    // ---- epilogue: x = x + leaky(h + bias); zero outside [0,NT)
    const float* bl = biases + l*NC;
    const bool last = (l == 5);
    #pragma unroll
    for (int mt=0;mt<4;++mt){
      const int cobase = (wm<<6) + (mt<<4) + (quad<<2);
      float bv[4];
      #pragma unroll
      for (int r=0;r<4;++r) bv[r] = bl[cobase + r];
      #pragma unroll
      for (int nt=0;nt<8;++nt){
        const int T = (wn<<7) + (nt<<4) + l15;
        const int idx = (T<<7) + (cobase ^ ((T&3)<<3));
        u32x4 xo = *(const u32x4*)&lx[idx];
        const int tg = row0g + T;
        const bool tv = ((u32)tg < (u32)NT);
        float nv[4];
        #pragma unroll
        for (int r=0;r<4;++r){
          float oldv = __uint_as_float(xo[r] & 0xFFFF0000u) + __uint_as_float(xo[r] << 16);
          float h = acc[mt][nt][r] + bv[r];
          h = (h >= 0.f) ? h : 0.2f*h;
          float xn = oldv + h;
          nv[r] = tv ? xn : 0.0f;
        }
        if (!last){
          u32x4 np;
          #pragma unroll
          for (int r=0;r<4;++r){
            u16 hh = bf16rn(nv[r]);
            u16 ll = bf16rn(nv[r] - __uint_as_float(((u32)hh)<<16));
            np[r] = ((u32)hh<<16) | ll;
          }
          *(u32x4*)&lx[idx] = np;
        } else {
          const bool rowok = mode ? (T >= 122 && T < 250) : (T < 128);
          if (rowok){
            float* po = xout + (size_t)(b*NC + cobase)*NT + tg;
            #pragma unroll
            for (int r=0;r<4;++r) po[(size_t)r*NT] = nv[r];
          }
        }
      }
    }
  }
}

// ============ K3a: up-proj on t-subsample (fp32, keys + coarse hist) ============
__global__ __launch_bounds__(256) void k_sub(const float* __restrict__ enc,
                                             const float* __restrict__ upw,
                                             const float* __restrict__ upb,
                                             u32* __restrict__ keys,
                                             u32* __restrict__ hist1){
  const int u0 = blockIdx.x * 64;
  const int i0 = blockIdx.y * 256;
  const int b  = blockIdx.z;
  __shared__ float uwl[32][68];
  __shared__ float ec[32][260];
  __shared__ u32 lh[1024];
  const int tid = threadIdx.x;
  for (int i=tid;i<1024;i+=256) lh[i] = 0u;
  const int ug = tid & 15;
  const int ig = tid >> 4;
  float acc[4][16];
  #pragma unroll
  for (int i=0;i<4;++i){
    #pragma unroll
    for (int j=0;j<16;++j) acc[i][j]=0.0f;
  }
  for (int c0=0;c0<NC;c0+=32){
    __syncthreads();
    #pragma unroll
    for (int i=0;i<8;++i){
      int flat = i*256+tid;
      uwl[flat & 31][flat >> 5] = upw[(size_t)(u0 + (flat>>5))*NC + c0 + (flat&31)];
    }
    #pragma unroll
    for (int i=0;i<32;++i){
      int flat = i*256+tid;
      ec[flat >> 8][flat & 255] = enc[(size_t)(b*NC + c0 + (flat>>8))*NT + (size_t)(i0 + (flat&255))*32];
    }
    __syncthreads();
    #pragma unroll 2
    for (int cc=0;cc<32;++cc){
      float a[4], bb[16];
      *(float4*)&a[0] = *(const float4*)&uwl[cc][ug*4];
      #pragma unroll
      for (int m=0;m<4;++m)
        *(float4*)&bb[m*4] = *(const float4*)&ec[cc][ig*16 + m*4];
      #pragma unroll
      for (int i=0;i<4;++i){
        #pragma unroll
        for (int j=0;j<16;++j)
          acc[i][j] = fmaf(a[i], bb[j], acc[i][j]);
      }
    }
  }
  #pragma unroll
  for (int i=0;i<4;++i){
    int u = u0 + ug*4 + i;
    float ub = upb[u];
    #pragma unroll
    for (int j=0;j<16;++j){
      float v = acc[i][j] + ub;
      u32 k = f2key(v);
      keys[(size_t)(b*NUP + u)*1024 + i0 + ig*16 + j] = k;
      atomicAdd(&lh[k >> 22], 1u);
    }
  }
  __syncthreads();
  for (int i=tid;i<1024;i+=256){
    u32 c = lh[i];
    if (c) atomicAdd(&hist1[b*1024 + i], c);
  }
}

// ============ K3sel: suffix-scan histogram, pick rank-64 bin ============
__global__ __launch_bounds__(256) void k_sel(const u32* __restrict__ hist,
                                             u32* __restrict__ cstar,
                                             u32* __restrict__ nab,
                                             u32* __restrict__ t0key,
                                             int phase){
  const int b = blockIdx.x;
  __shared__ u32 s1[1024];
  __shared__ u32 s2[1024];
  __shared__ int red[256];
  const int tid = threadIdx.x;
  for (int i=tid;i<1024;i+=256) s1[i] = hist[b*1024 + i];
  __syncthreads();
  u32* cur = s1; u32* nxt = s2;
  for (int off=1; off<1024; off<<=1){
    for (int i=tid;i<1024;i+=256){
      u32 v = cur[i];
      if (i + off < 1024) v += cur[i+off];
      nxt[i] = v;
    }
    __syncthreads();
    u32* t = cur; cur = nxt; nxt = t;
  }
  u32 off0 = (phase==1) ? 0u : nab[b];
  int best = -1;
  for (int i=tid;i<1024;i+=256)
    if (off0 + cur[i] >= 64u && i > best) best = i;
  red[tid] = best;
  __syncthreads();
  for (int st=128; st>0; st>>=1){
    if (tid < st) red[tid] = max(red[tid], red[tid+st]);
    __syncthreads();
  }
  if (tid == 0){
    int bi = (red[0] < 0) ? 0 : red[0];
    if (phase == 1){
      cstar[b] = (u32)bi;
      nab[b] = (bi < 1023) ? cur[bi+1] : 0u;
    } else {
      t0key[b] = (cstar[b] << 22) | (((u32)bi) << 12);
    }
  }
}

// ============ K3h2: fine histogram within coarse bin ============
__global__ void k_h2(const u32* __restrict__ keys, const u32* __restrict__ cstar,
                     u32* __restrict__ hist2){
  const u32 c0 = cstar[0], c1 = cstar[1];
  int i = blockIdx.x*256 + threadIdx.x;
  const int total = NB*NUP*1024;
  const int stride = gridDim.x*256;
  for (; i < total; i += stride){
    u32 k = keys[i];
    u32 cs = (i >> 21) ? c1 : c0;
    if ((k >> 22) == cs) atomicAdd(&hist2[((u32)(i>>21)<<10) + ((k>>12) & 1023u)], 1u);
  }
}

// ============ K3b: full up-proj — bf16x3 MFMA, append candidates >= threshold ============
__global__ __launch_bounds__(256,2) void k_up(const float* __restrict__ enc,
    const u16* __restrict__ wf, const float* __restrict__ upb,
    const u32* __restrict__ t0key, float* __restrict__ cval,
    int* __restrict__ cidx, int* __restrict__ counts){
  __shared__ u32 lx[128*32];
  const int tid = threadIdx.x;
  const int u0 = blockIdx.x << 7;
  const int t0 = blockIdx.y << 7;
  const int b  = blockIdx.z;
  const int lane = tid & 63, w = tid >> 6;
  const int wy = w >> 1, wx = w & 1;
  const int quad = lane >> 4, l15 = lane & 15;
  const int ci_l = tid >> 3, sub = tid & 7;
  f32x4 acc[4][4] = {};
  for (int cc = 0; cc < 4; ++cc){
    __syncthreads();
    const float* xr = enc + (size_t)(b*NC + cc*32 + ci_l)*NT + t0;
    #pragma unroll
    for (int j=0;j<16;++j){
      int tl = sub + (j<<3);
      float v = xr[tl];
      u16 h = bf16rn(v);
      u16 lo = bf16rn(v - __uint_as_float(((u32)h)<<16));
      lx[(tl<<5) + (ci_l ^ ((tl&3)<<3))] = ((u32)h<<16) | lo;
    }
    __syncthreads();
    short8 ah[4], al[4];
    #pragma unroll
    for (int mt=0; mt<4; ++mt){
      const u16* p = wf + (size_t)(cc*128 + (u0>>4) + wy*4 + mt)*1024 + (lane<<3);
      ah[mt] = *(const short8*)p;
      al[mt] = *(const short8*)(p + 512);
    }
    short8 xh[4], xl[4];
    #pragma unroll
    for (int nt=0; nt<4; ++nt){
      int T = (wx<<6) + (nt<<4) + l15;
      int idx = (T<<5) + ((quad<<3) ^ ((T&3)<<3));
      unpack8(&lx[idx], xh[nt], xl[nt]);
    }
    #pragma unroll
    for (int mt=0; mt<4; ++mt){
      #pragma unroll
      for (int nt=0; nt<4; ++nt){
        acc[mt][nt] = __builtin_amdgcn_mfma_f32_16x16x32_bf16(ah[mt], xh[nt], acc[mt][nt], 0,0,0);
        acc[mt][nt] = __builtin_amdgcn_mfma_f32_16x16x32_bf16(ah[mt], xl[nt], acc[mt][nt], 0,0,0);
        acc[mt][nt] = __builtin_amdgcn_mfma_f32_16x16x32_bf16(al[mt], xh[nt], acc[mt][nt], 0,0,0);
      }
    }
  }
  float T0 = key2f(t0key[b]);
  T0 -= fabsf(T0)*3e-4f + 1e-5f;
  #pragma unroll
  for (int mt=0; mt<4; ++mt){
    #pragma unroll
    for (int r=0; r<4; ++r){
      int u = u0 + (wy<<6) + (mt<<4) + (quad<<2) + r;
      float ub = upb[u];
      #pragma unroll
      for (int nt=0; nt<4; ++nt){
        float v = acc[mt][nt][r] + ub;
        if (v >= T0){
          int slot = atomicAdd(&counts[b], 1);
          if (slot < CAP){
            cval[b*CAP + slot] = v;
            cidx[b*CAP + slot] = u*NT + (t0 + (wx<<6) + (nt<<4) + l15);
          }
        }
      }
    }
  }
}

// ============ K3c: exact top-64 of candidates ============
__global__ __launch_bounds__(256) void k_top(const float* __restrict__ cval,
                                             const int* __restrict__ cidx,
                                             const int* __restrict__ counts,
                                             float* __restrict__ tv,
                                             int* __restrict__ ti){
  const int b = blockIdx.x;
  __shared__ float lv[CAP];
  __shared__ float sv[256];
  __shared__ int   si[256];
  const int tid = threadIdx.x;
  int n = counts[b]; if (n > CAP) n = CAP;
  for (int i=tid;i<n;i+=256) lv[i] = cval[b*CAP+i];
  __syncthreads();
  for (int r=0;r<64;++r){
    float best = -3.4e38f; int bi = -1;
    for (int i=tid;i<n;i+=256){
      float v = lv[i];
      if (v > best){ best = v; bi = i; }
    }
    sv[tid]=best; si[tid]=bi;
    __syncthreads();
    for (int st=128; st>0; st>>=1){
      if (tid < st && sv[tid+st] > sv[tid]){ sv[tid]=sv[tid+st]; si[tid]=si[tid+st]; }
      __syncthreads();
    }
    if (tid == 0){
      int kb = si[0];
      if (kb >= 0){
        tv[b*64+r] = sv[0];
        ti[b*64+r] = cidx[b*CAP+kb];
        lv[kb] = -3.4e38f;
      } else { tv[b*64+r] = 0.0f; ti[b*64+r] = 0; }
    }
    __syncthreads();
  }
}

// ============ K4a: fill decoder input with down_b ============
__global__ void k_fill(float* __restrict__ dst, const float* __restrict__ downb){
  const int bc = blockIdx.x;
  const int c = bc & 127;
  float v = downb[c];
  float4 vv; vv.x=v; vv.y=v; vv.z=v; vv.w=v;
  float4* p = (float4*)(dst + (size_t)bc*NT);
  for (int i=threadIdx.x; i < NT/4; i += 256) p[i] = vv;
}

// ============ K4b: scatter spikes through down_w ============
__global__ void k_scat(float* __restrict__ dst, const float* __restrict__ downw,
                       const float* __restrict__ tv, const int* __restrict__ ti){
  const int b = blockIdx.x, r = blockIdx.y;
  float v = tv[b*64+r];
  int idx = ti[b*64+r];
  int u = idx / NT, t = idx - u*NT;
  int c = threadIdx.x;
  atomicAdd(&dst[(size_t)(b*NC+c)*NT + t], downw[(size_t)c*NUP + u] * v);
}

// ============ K6: transposed filterbank synthesis (fp32, conflict-free, 2 blocks/CU) ============
#define TS 4096
__global__ __launch_bounds__(256) void k_syn(const float* __restrict__ dec,
                                             const float* __restrict__ fb,
                                             float* __restrict__ part){
  const int ts = blockIdx.x;    // 8
  const int cs = blockIdx.y;    // 32 (4 channels each)
  const int b  = blockIdx.z;
  const int t0 = ts * TS;
  __shared__ float win2[16*289 + 8];
  __shared__ float fbl[512];
  const int tid = threadIdx.x;
  const int tl = tid * 16;
  float acc[16];
  #pragma unroll
  for (int j=0;j<16;++j) acc[j] = 0.0f;
  for (int c = cs*4; c < cs*4+4; ++c){
    __syncthreads();
    for (int i=tid; i < TS+511; i += 256){
      int t = t0 - 255 + i;
      win2[(i & 15)*289 + (i >> 4)] = ((u32)t < (u32)NT) ? dec[(size_t)(b*NC+c)*NT + t] : 0.0f;
    }
    for (int i=tid; i<512; i+=256) fbl[i] = fb[c*KFB + i];
    __syncthreads();
    float w[23];
    #pragma unroll
    for (int k=0;k<23;++k){
      int i = tl + 504 + k;
      w[k] = win2[(i & 15)*289 + (i >> 4)];
    }
    for (int G=0; G<64; ++G){
      float4 f0 = *(const float4*)&fbl[G*8];
      float4 f1 = *(const float4*)&fbl[G*8+4];
      float fq[8] = {f0.x, f0.y, f0.z, f0.w, f1.x, f1.y, f1.z, f1.w};
      #pragma unroll
      for (int q=0;q<8;++q){
        #pragma unroll
        for (int jj=0;jj<16;++jj)
          acc[jj] = fmaf(fq[q], w[7-q+jj], acc[jj]);
      }
      if (G != 63){
        #pragma unroll
        for (int k=22;k>=8;--k) w[k] = w[k-8];
        #pragma unroll
        for (int k=0;k<8;++k){
          int i = tl + 496 - 8*G + k;
          w[k] = win2[(i & 15)*289 + (i >> 4)];
        }
      }
    }
  }
  float* po = &part[(size_t)(cs*NB + b)*NT + t0 + tl];
  #pragma unroll
  for (int m=0;m<4;++m){
    float4 ov; ov.x=acc[m*4+0]; ov.y=acc[m*4+1]; ov.z=acc[m*4+2]; ov.w=acc[m*4+3];
    *(float4*)&po[m*4] = ov;
  }
}

// ============ K6r: reduce partials -> out ============
__global__ void k_red(const float* __restrict__ part, float* __restrict__ out){
  int i = blockIdx.x*256 + threadIdx.x;
  float s = 0.0f;
  #pragma unroll
  for (int cs=0;cs<32;++cs) s += part[(size_t)cs*(NB*NT) + i];
  out[i] = s;
}

extern "C" void kernel_launch(void* const* d_in, const int* in_sizes, int n_in,
                              void* d_out, int out_size, void* d_ws, size_t ws_size,
                              hipStream_t stream){
  const float* x    = (const float*)d_in[0];
  const float* fb   = (const float*)d_in[1];
  const float* encw = (const float*)d_in[2];
  const float* encb = (const float*)d_in[3];
  const float* upw  = (const float*)d_in[4];
  const float* upb  = (const float*)d_in[5];
  const float* dnw  = (const float*)d_in[6];
  const float* dnb  = (const float*)d_in[7];
  const float* decw = (const float*)d_in[8];
  const float* decb = (const float*)d_in[9];
  float* out = (float*)d_out;
  char* ws = (char*)d_ws;

  size_t o = 0;
  float* bufA = (float*)(ws + o); o += (size_t)NB*NC*NT*4;
  float* bufB = (float*)(ws + o); o += (size_t)NB*NC*NT*4;
  u32*  keys  = (u32*)(ws + o);   o += (size_t)NB*NUP*1024*4;   // also reused as `part` later
  u32*  hist1 = (u32*)(ws + o);   o += 1024*NB*4;
  u32*  hist2 = (u32*)(ws + o);   o += 1024*NB*4;
  u32*  cstar = (u32*)(ws + o);   o += 64;
  u32*  nab   = (u32*)(ws + o);   o += 64;
  u32*  t0k   = (u32*)(ws + o);   o += 64;
  int*  cnt   = (int*)(ws + o);   o += 64;
  float* tv   = (float*)(ws + o); o += NB*64*4;
  int*  ti    = (int*)(ws + o);   o += NB*64*4;
  float* cval = (float*)(ws + o); o += (size_t)NB*CAP*4;
  int*  cidx  = (int*)(ws + o);   o += (size_t)NB*CAP*4;
  u16*  wdil  = (u16*)(ws + o);   o += (size_t)12*65536*2;
  u16*  wup   = (u16*)(ws + o);   o += (size_t)4*128*1024*2;
  u16*  wfb   = (u16*)(ws + o);   o += (size_t)128*1024*2;
  float* part = (float*)keys;     // keys dead after k_h2; 32*NB*NT*4 = 8.4 MB <= 16.8 MB

  k_init<<<dim3(16), dim3(256), 0, stream>>>(hist1, hist2, cnt);
  k_prep<<<dim3(352), dim3(256), 0, stream>>>(encw, decw, upw, fb, wdil, wup, wfb);
  k_fb<<<dim3(256,NB), dim3(256), 0, stream>>>(x, wfb, bufA);

  // fused encoder stack: bufA -> bufB
  k_stack<<<dim3(256,NB), dim3(256), 131072, stream>>>(bufA, bufB, wdil, encb, 0);

  k_sub<<<dim3(32,4,NB), dim3(256), 0, stream>>>(bufB, upw, upb, keys, hist1);
  k_sel<<<dim3(NB), dim3(256), 0, stream>>>(hist1, cstar, nab, t0k, 1);
  k_h2 <<<dim3(4096), dim3(256), 0, stream>>>(keys, cstar, hist2);
  k_sel<<<dim3(NB), dim3(256), 0, stream>>>(hist2, cstar, nab, t0k, 2);
  k_up <<<dim3(16,256,NB), dim3(256), 0, stream>>>(bufB, wup, upb, t0k, cval, cidx, cnt);
  k_top<<<dim3(NB), dim3(256), 0, stream>>>(cval, cidx, cnt, tv, ti);

  // decoder input: bufA = down_b + spikes
  k_fill<<<dim3(NB*NC), dim3(256), 0, stream>>>(bufA, dnb);
  k_scat<<<dim3(NB,64), dim3(128), 0, stream>>>(bufA, dnw, tv, ti);

  // fused decoder stack: bufA -> bufB
  k_stack<<<dim3(256,NB), dim3(256), 131072, stream>>>(bufA, bufB, wdil + (size_t)6*65536, decb, 1);

  k_syn<<<dim3(8,32,NB), dim3(256), 0, stream>>>(bufB, fb, part);
  k_red<<<dim3(256), dim3(256), 0, stream>>>(part, out);
}

// Round 5
// 864.471 us; speedup vs baseline: 2.9242x; 1.2897x over previous
//
#include <hip/hip_runtime.h>
#include <stdint.h>

#define NB  2
#define NC  128
#define NT  32768
#define KFB 512
#define NUP 2048
#define CAP 14336

typedef unsigned int u32;
typedef unsigned short u16;
typedef short s16;
typedef float f32x4 __attribute__((ext_vector_type(4)));
typedef s16 short8 __attribute__((ext_vector_type(8)));
typedef u32 u32x4 __attribute__((ext_vector_type(4)));

__device__ __forceinline__ u32 f2key(float v){
  u32 u = __float_as_uint(v);
  return (u & 0x80000000u) ? ~u : (u | 0x80000000u);
}
__device__ __forceinline__ float key2f(u32 k){
  u32 u = (k & 0x80000000u) ? (k & 0x7FFFFFFFu) : ~k;
  return __uint_as_float(u);
}
__device__ __forceinline__ u16 bf16rn(float v){
  u32 u = __float_as_uint(v);
  return (u16)((u + 0x7FFFu + ((u>>16)&1u)) >> 16);
}
__device__ __forceinline__ u32 packhl(float v){
  u16 h = bf16rn(v);
  u16 lo = bf16rn(v - __uint_as_float(((u32)h)<<16));
  return ((u32)h<<16) | lo;
}
__device__ __forceinline__ void unpack8(const u32* p, short8& xh, short8& xl){
  u32x4 r0 = *(const u32x4*)p;
  u32x4 r1 = *(const u32x4*)(p + 4);
  union { u32 u[4]; short8 v; } H, L;
  H.u[0] = __builtin_amdgcn_perm(r0.y, r0.x, 0x07060302u);
  H.u[1] = __builtin_amdgcn_perm(r0.w, r0.z, 0x07060302u);
  H.u[2] = __builtin_amdgcn_perm(r1.y, r1.x, 0x07060302u);
  H.u[3] = __builtin_amdgcn_perm(r1.w, r1.z, 0x07060302u);
  L.u[0] = __builtin_amdgcn_perm(r0.y, r0.x, 0x05040100u);
  L.u[1] = __builtin_amdgcn_perm(r0.w, r0.z, 0x05040100u);
  L.u[2] = __builtin_amdgcn_perm(r1.y, r1.x, 0x05040100u);
  L.u[3] = __builtin_amdgcn_perm(r1.w, r1.z, 0x05040100u);
  xh = H.v; xl = L.v;
}

// LDS row stride for [T][ci] tiles: 132 ≡ 4 (mod 32) -> uniform banks for
// b128 ops at 4-aligned ci with lane-varying T (8 slots/bank = LDS floor).
#define RS 132

// ============ K0: init ============
__global__ void k_init(u32* __restrict__ h1, u32* __restrict__ h2, int* __restrict__ counts){
  int i = blockIdx.x*256 + threadIdx.x;
  if (i < 2048) h1[i] = 0u;
  else if (i < 4096) h2[i-2048] = 0u;
  if (i < NB) counts[i] = 0;
}

// ============ K_prep: split weights to bf16 hi/lo in MFMA A-fragment order ============
__global__ __launch_bounds__(256) void k_prep(const float* __restrict__ encw,
    const float* __restrict__ decw, const float* __restrict__ upw,
    const float* __restrict__ fbw,
    u16* __restrict__ wdil, u16* __restrict__ wup, u16* __restrict__ wfb){
  int g = blockIdx.x*256 + threadIdx.x;
  if (g < 49152){
    int l = g & 63, mt = (g>>6)&7, s = (g>>9)&7, layer = g>>12;
    const float* W = (layer < 6) ? (encw + (size_t)layer*NC*NC*2)
                                 : (decw + (size_t)(layer-6)*NC*NC*2);
    int co = mt*16 + (l & 15);
    int kb = s*32 + ((l>>4)<<3);
    union { u16 h[8]; u32x4 q; } H, L;
    #pragma unroll
    for (int j=0;j<8;++j){
      int k = kb + j;
      float v = W[((size_t)co*NC + (k&127))*2 + (k>>7)];
      u16 h = bf16rn(v);
      H.h[j] = h;
      L.h[j] = bf16rn(v - __uint_as_float(((u32)h)<<16));
    }
    int unit = g >> 6;
    *(u32x4*)(wdil + (size_t)unit*1024 + (l<<3)) = H.q;
    *(u32x4*)(wdil + (size_t)unit*1024 + 512 + (l<<3)) = L.q;
  } else if (g < 81920){
    int g2 = g - 49152;
    int l = g2 & 63, umt = (g2>>6)&127, s = g2>>13;
    int u = umt*16 + (l & 15);
    int kb = s*32 + ((l>>4)<<3);
    union { u16 h[8]; u32x4 q; } H, L;
    #pragma unroll
    for (int j=0;j<8;++j){
      float v = upw[(size_t)u*NC + kb + j];
      u16 h = bf16rn(v);
      H.h[j] = h;
      L.h[j] = bf16rn(v - __uint_as_float(((u32)h)<<16));
    }
    int unit = g2 >> 6;
    *(u32x4*)(wup + (size_t)unit*1024 + (l<<3)) = H.q;
    *(u32x4*)(wup + (size_t)unit*1024 + 512 + (l<<3)) = L.q;
  } else if (g < 90112){
    int g3 = g - 81920;
    int l = g3 & 63, mt = (g3>>6)&7, s = g3>>9;
    int c = mt*16 + (l & 15);
    int kb = s*32 + ((l>>4)<<3);
    union { u16 h[8]; u32x4 q; } H, L;
    #pragma unroll
    for (int j=0;j<8;++j){
      float v = fbw[(size_t)c*KFB + kb + j];
      u16 h = bf16rn(v);
      H.h[j] = h;
      L.h[j] = bf16rn(v - __uint_as_float(((u32)h)<<16));
    }
    int unit = g3 >> 6;
    *(u32x4*)(wfb + (size_t)unit*1024 + (l<<3)) = H.q;
    *(u32x4*)(wfb + (size_t)unit*1024 + 512 + (l<<3)) = L.q;
  }
}

// ============ K1: filterbank analysis — bf16x3 MFMA ============
__global__ __launch_bounds__(256) void k_fb(const float* __restrict__ x,
    const u16* __restrict__ wfb, float* __restrict__ spec){
  __shared__ u32 xw[640];
  const int tid = threadIdx.x;
  const int t0 = blockIdx.x << 7;
  const int b  = blockIdx.y;
  const int lane = tid & 63, w = tid >> 6;
  const int wy = w >> 1, wx = w & 1;
  const int quad = lane >> 4, l15 = lane & 15;
  for (int i = tid; i < 640; i += 256){
    int t = t0 - 256 + i;
    float v = ((u32)t < (u32)NT) ? x[b*NT + t] : 0.0f;
    xw[i] = packhl(v);
  }
  __syncthreads();
  f32x4 acc[4][4] = {};
  for (int s = 0; s < 16; ++s){
    short8 ah[4], al[4];
    #pragma unroll
    for (int mt=0; mt<4; ++mt){
      const u16* p = wfb + (size_t)(s*8 + wy*4 + mt)*1024 + (lane<<3);
      ah[mt] = *(const short8*)p;
      al[mt] = *(const short8*)(p + 512);
    }
    short8 xh[4], xl[4];
    #pragma unroll
    for (int nt=0; nt<4; ++nt){
      int base = s*32 + quad*8 + (wx<<6) + (nt<<4) + l15;
      u32 r[8];
      #pragma unroll
      for (int j=0;j<8;++j) r[j] = xw[base + j];
      union { u32 u[4]; short8 v; } H, L;
      H.u[0] = __builtin_amdgcn_perm(r[1], r[0], 0x07060302u);
      H.u[1] = __builtin_amdgcn_perm(r[3], r[2], 0x07060302u);
      H.u[2] = __builtin_amdgcn_perm(r[5], r[4], 0x07060302u);
      H.u[3] = __builtin_amdgcn_perm(r[7], r[6], 0x07060302u);
      L.u[0] = __builtin_amdgcn_perm(r[1], r[0], 0x05040100u);
      L.u[1] = __builtin_amdgcn_perm(r[3], r[2], 0x05040100u);
      L.u[2] = __builtin_amdgcn_perm(r[5], r[4], 0x05040100u);
      L.u[3] = __builtin_amdgcn_perm(r[7], r[6], 0x05040100u);
      xh[nt] = H.v; xl[nt] = L.v;
    }
    #pragma unroll
    for (int mt=0; mt<4; ++mt){
      #pragma unroll
      for (int nt=0; nt<4; ++nt){
        acc[mt][nt] = __builtin_amdgcn_mfma_f32_16x16x32_bf16(ah[mt], xh[nt], acc[mt][nt], 0,0,0);
        acc[mt][nt] = __builtin_amdgcn_mfma_f32_16x16x32_bf16(ah[mt], xl[nt], acc[mt][nt], 0,0,0);
        acc[mt][nt] = __builtin_amdgcn_mfma_f32_16x16x32_bf16(al[mt], xh[nt], acc[mt][nt], 0,0,0);
      }
    }
  }
  #pragma unroll
  for (int mt=0; mt<4; ++mt){
    #pragma unroll
    for (int r=0; r<4; ++r){
      const int c = (wy<<6) + (mt<<4) + (quad<<2) + r;
      float* po = spec + (size_t)(b*NC+c)*NT + t0 + (wx<<6) + l15;
      #pragma unroll
      for (int nt=0; nt<4; ++nt) po[nt<<4] = acc[mt][nt][r];
    }
  }
}

// ============ K2: fused 6-layer dilated residual stack — bf16x3 MFMA, all-LDS ============
// 512 threads = 8 waves (wm 0..1 co-half, wn 0..3 t-quarter); wave tile 64co x 64t.
// LDS: 256 rows x RS(132) u32 packed hi/lo = 132 KB -> 1 block/CU, 2 waves/SIMD.
__global__ __launch_bounds__(512,2) void k_stack(const float* __restrict__ xin,
    float* __restrict__ xout, const u16* __restrict__ wf,
    const float* __restrict__ biases, int mode){
  extern __shared__ u32 lx[];           // [row 256][RS]
  const int tid = threadIdx.x;
  const int b  = blockIdx.y;
  const int T0 = blockIdx.x << 7;
  const int row0g = mode ? (T0 - 122) : T0;   // global t of LDS row 0
  const int lane = tid & 63, w = tid >> 6;
  const int wm = w >> 2, wn = w & 3;
  const int quad = lane >> 4, l15 = lane & 15;
  // ---- stage-in: row = tid/2, 64 ci per thread, b128 packed writes
  {
    const float* xb = xin + (size_t)b*NC*NT;
    const int row = tid >> 1;
    const int ci0 = (tid & 1) << 6;
    const int tg = row0g + row;
    const bool ok = ((u32)tg < (u32)NT);
    const float* src = xb + (size_t)ci0*NT + tg;
    u32* dst = lx + row*RS + ci0;
    #pragma unroll
    for (int g=0; g<16; ++g){
      u32x4 q;
      #pragma unroll
      for (int k=0;k<4;++k){
        float v = ok ? src[(size_t)(g*4 + k)*NT] : 0.0f;
        q[k] = packhl(v);
      }
      *(u32x4*)(dst + g*4) = q;
    }
  }
  const int dils[6] = {1,3,9,27,81,1};
  #pragma unroll 1
  for (int l = 0; l < 6; ++l){
    const int d = dils[l];
    const int o0 = mode ? -d : 0;
    const int o1 = mode ? 0 : d;
    const u16* wl = wf + ((size_t)l << 16);
    __syncthreads();
    f32x4 acc[4][4] = {};
    #pragma unroll 1
    for (int s = 0; s < 8; ++s){
      short8 ah[4], al[4];
      #pragma unroll
      for (int mt=0;mt<4;++mt){
        const u16* p = wl + (size_t)(((s<<3) + (wm<<2) + mt) << 10) + (lane<<3);
        ah[mt] = *(const short8*)p;
        al[mt] = *(const short8*)(p + 512);
      }
      const int o = (s >= 4) ? o1 : o0;
      const int cig = (s & 3) << 5;
      #pragma unroll
      for (int nt=0;nt<4;++nt){
        const int T = ((wn<<6) + (nt<<4) + l15 + o) & 255;
        const int idx = T*RS + cig + (quad<<3);
        short8 xh, xl;
        unpack8(&lx[idx], xh, xl);
        #pragma unroll
        for (int mt=0;mt<4;++mt){
          acc[mt][nt] = __builtin_amdgcn_mfma_f32_16x16x32_bf16(ah[mt], xh, acc[mt][nt], 0,0,0);
          acc[mt][nt] = __builtin_amdgcn_mfma_f32_16x16x32_bf16(ah[mt], xl, acc[mt][nt], 0,0,0);
          acc[mt][nt] = __builtin_amdgcn_mfma_f32_16x16x32_bf16(al[mt], xh, acc[mt][nt], 0,0,0);
        }
      }
    }
    __syncthreads();
    // ---- epilogue: x = x + leaky(h + bias); zero outside [0,NT)
    const float* bl = biases + l*NC;
    const bool last = (l == 5);
    #pragma unroll
    for (int mt=0;mt<4;++mt){
      const int cobase = (wm<<6) + (mt<<4) + (quad<<2);
      float bv[4];
      #pragma unroll
      for (int r=0;r<4;++r) bv[r] = bl[cobase + r];
      #pragma unroll
      for (int nt=0;nt<4;++nt){
        const int T = (wn<<6) + (nt<<4) + l15;
        const int idx = T*RS + cobase;
        u32x4 xo = *(const u32x4*)&lx[idx];
        const int tg = row0g + T;
        const bool tv = ((u32)tg < (u32)NT);
        float nv[4];
        #pragma unroll
        for (int r=0;r<4;++r){
          float oldv = __uint_as_float(xo[r] & 0xFFFF0000u) + __uint_as_float(xo[r] << 16);
          float h = acc[mt][nt][r] + bv[r];
          h = (h >= 0.f) ? h : 0.2f*h;
          float xn = oldv + h;
          nv[r] = tv ? xn : 0.0f;
        }
        if (!last){
          u32x4 np;
          #pragma unroll
          for (int r=0;r<4;++r) np[r] = packhl(nv[r]);
          *(u32x4*)&lx[idx] = np;
        } else {
          const bool rowok = mode ? (T >= 122 && T < 250) : (T < 128);
          if (rowok){
            float* po = xout + (size_t)(b*NC + cobase)*NT + tg;
            #pragma unroll
            for (int r=0;r<4;++r) po[(size_t)r*NT] = nv[r];
          }
        }
      }
    }
  }
}

// ============ K3a: up-proj on t-subsample (fp32, keys + coarse hist) ============
__global__ __launch_bounds__(256) void k_sub(const float* __restrict__ enc,
                                             const float* __restrict__ upw,
                                             const float* __restrict__ upb,
                                             u32* __restrict__ keys,
                                             u32* __restrict__ hist1){
  const int u0 = blockIdx.x * 64;
  const int i0 = blockIdx.y * 256;
  const int b  = blockIdx.z;
  __shared__ float uwl[32][68];
  __shared__ float ec[32][260];
  __shared__ u32 lh[1024];
  const int tid = threadIdx.x;
  for (int i=tid;i<1024;i+=256) lh[i] = 0u;
  const int ug = tid & 15;
  const int ig = tid >> 4;
  float acc[4][16];
  #pragma unroll
  for (int i=0;i<4;++i){
    #pragma unroll
    for (int j=0;j<16;++j) acc[i][j]=0.0f;
  }
  for (int c0=0;c0<NC;c0+=32){
    __syncthreads();
    #pragma unroll
    for (int i=0;i<8;++i){
      int flat = i*256+tid;
      uwl[flat & 31][flat >> 5] = upw[(size_t)(u0 + (flat>>5))*NC + c0 + (flat&31)];
    }
    #pragma unroll
    for (int i=0;i<32;++i){
      int flat = i*256+tid;
      ec[flat >> 8][flat & 255] = enc[(size_t)(b*NC + c0 + (flat>>8))*NT + (size_t)(i0 + (flat&255))*32];
    }
    __syncthreads();
    #pragma unroll 2
    for (int cc=0;cc<32;++cc){
      float a[4], bb[16];
      *(float4*)&a[0] = *(const float4*)&uwl[cc][ug*4];
      #pragma unroll
      for (int m=0;m<4;++m)
        *(float4*)&bb[m*4] = *(const float4*)&ec[cc][ig*16 + m*4];
      #pragma unroll
      for (int i=0;i<4;++i){
        #pragma unroll
        for (int j=0;j<16;++j)
          acc[i][j] = fmaf(a[i], bb[j], acc[i][j]);
      }
    }
  }
  #pragma unroll
  for (int i=0;i<4;++i){
    int u = u0 + ug*4 + i;
    float ub = upb[u];
    #pragma unroll
    for (int j=0;j<16;++j){
      float v = acc[i][j] + ub;
      u32 k = f2key(v);
      keys[(size_t)(b*NUP + u)*1024 + i0 + ig*16 + j] = k;
      atomicAdd(&lh[k >> 22], 1u);
    }
  }
  __syncthreads();
  for (int i=tid;i<1024;i+=256){
    u32 c = lh[i];
    if (c) atomicAdd(&hist1[b*1024 + i], c);
  }
}

// ============ K3sel: suffix-scan histogram, pick rank-64 bin ============
__global__ __launch_bounds__(256) void k_sel(const u32* __restrict__ hist,
                                             u32* __restrict__ cstar,
                                             u32* __restrict__ nab,
                                             u32* __restrict__ t0key,
                                             int phase){
  const int b = blockIdx.x;
  __shared__ u32 s1[1024];
  __shared__ u32 s2[1024];
  __shared__ int red[256];
  const int tid = threadIdx.x;
  for (int i=tid;i<1024;i+=256) s1[i] = hist[b*1024 + i];
  __syncthreads();
  u32* cur = s1; u32* nxt = s2;
  for (int off=1; off<1024; off<<=1){
    for (int i=tid;i<1024;i+=256){
      u32 v = cur[i];
      if (i + off < 1024) v += cur[i+off];
      nxt[i] = v;
    }
    __syncthreads();
    u32* t = cur; cur = nxt; nxt = t;
  }
  u32 off0 = (phase==1) ? 0u : nab[b];
  int best = -1;
  for (int i=tid;i<1024;i+=256)
    if (off0 + cur[i] >= 64u && i > best) best = i;
  red[tid] = best;
  __syncthreads();
  for (int st=128; st>0; st>>=1){
    if (tid < st) red[tid] = max(red[tid], red[tid+st]);
    __syncthreads();
  }
  if (tid == 0){
    int bi = (red[0] < 0) ? 0 : red[0];
    if (phase == 1){
      cstar[b] = (u32)bi;
      nab[b] = (bi < 1023) ? cur[bi+1] : 0u;
    } else {
      t0key[b] = (cstar[b] << 22) | (((u32)bi) << 12);
    }
  }
}

// ============ K3h2: fine histogram within coarse bin ============
__global__ void k_h2(const u32* __restrict__ keys, const u32* __restrict__ cstar,
                     u32* __restrict__ hist2){
  const u32 c0 = cstar[0], c1 = cstar[1];
  int i = blockIdx.x*256 + threadIdx.x;
  const int total = NB*NUP*1024;
  const int stride = gridDim.x*256;
  for (; i < total; i += stride){
    u32 k = keys[i];
    u32 cs = (i >> 21) ? c1 : c0;
    if ((k >> 22) == cs) atomicAdd(&hist2[((u32)(i>>21)<<10) + ((k>>12) & 1023u)], 1u);
  }
}

// ============ K3b: full up-proj — bf16x3 MFMA, t-tile resident, u-chunk loop ============
// Block: 128 t (staged once to LDS) x all 2048 u in 16 chunks. 2 blocks/CU.
__global__ __launch_bounds__(256,2) void k_up(const float* __restrict__ enc,
    const u16* __restrict__ wf, const float* __restrict__ upb,
    const u32* __restrict__ t0key, float* __restrict__ cval,
    int* __restrict__ cidx, int* __restrict__ counts){
  extern __shared__ u32 lx[];   // [128][RS]
  const int tid = threadIdx.x;
  const int t0 = blockIdx.x << 7;
  const int b  = blockIdx.y;
  const int lane = tid & 63, w = tid >> 6;
  const int wy = w >> 1, wx = w & 1;
  const int quad = lane >> 4, l15 = lane & 15;
  // ---- stage enc tile once
  {
    const float* xb = enc + (size_t)b*NC*NT + t0;
    const int row = tid >> 1;
    const int ci0 = (tid & 1) << 6;
    const float* src = xb + (size_t)ci0*NT + row;
    u32* dst = lx + row*RS + ci0;
    #pragma unroll
    for (int g=0; g<16; ++g){
      u32x4 q;
      #pragma unroll
      for (int k=0;k<4;++k) q[k] = packhl(src[(size_t)(g*4 + k)*NT]);
      *(u32x4*)(dst + g*4) = q;
    }
  }
  __syncthreads();
  float T0 = key2f(t0key[b]);
  T0 -= fabsf(T0)*3e-4f + 1e-5f;
  #pragma unroll 1
  for (int uc = 0; uc < 16; ++uc){
    f32x4 acc[4][4] = {};
    #pragma unroll 1
    for (int s = 0; s < 4; ++s){
      short8 ah[4], al[4];
      #pragma unroll
      for (int mt=0;mt<4;++mt){
        const u16* p = wf + (size_t)((s*128 + uc*8 + wy*4 + mt) << 10) + (lane<<3);
        ah[mt] = *(const short8*)p;
        al[mt] = *(const short8*)(p + 512);
      }
      const int cig = s << 5;
      #pragma unroll
      for (int nt=0;nt<4;++nt){
        const int T = (wx<<6) + (nt<<4) + l15;
        short8 xh, xl;
        unpack8(&lx[T*RS + cig + (quad<<3)], xh, xl);
        #pragma unroll
        for (int mt=0;mt<4;++mt){
          acc[mt][nt] = __builtin_amdgcn_mfma_f32_16x16x32_bf16(ah[mt], xh, acc[mt][nt], 0,0,0);
          acc[mt][nt] = __builtin_amdgcn_mfma_f32_16x16x32_bf16(ah[mt], xl, acc[mt][nt], 0,0,0);
          acc[mt][nt] = __builtin_amdgcn_mfma_f32_16x16x32_bf16(al[mt], xh, acc[mt][nt], 0,0,0);
        }
      }
    }
    #pragma unroll
    for (int mt=0; mt<4; ++mt){
      #pragma unroll
      for (int r=0; r<4; ++r){
        int u = uc*128 + (wy<<6) + (mt<<4) + (quad<<2) + r;
        float ub = upb[u];
        #pragma unroll
        for (int nt=0; nt<4; ++nt){
          float v = acc[mt][nt][r] + ub;
          if (v >= T0){
            int slot = atomicAdd(&counts[b], 1);
            if (slot < CAP){
              cval[b*CAP + slot] = v;
              cidx[b*CAP + slot] = u*NT + (t0 + (wx<<6) + (nt<<4) + l15);
            }
          }
        }
      }
    }
  }
}

// ============ K3c: exact top-64 of candidates ============
__global__ __launch_bounds__(256) void k_top(const float* __restrict__ cval,
                                             const int* __restrict__ cidx,
                                             const int* __restrict__ counts,
                                             float* __restrict__ tv,
                                             int* __restrict__ ti){
  const int b = blockIdx.x;
  __shared__ float lv[CAP];
  __shared__ float sv[256];
  __shared__ int   si[256];
  const int tid = threadIdx.x;
  int n = counts[b]; if (n > CAP) n = CAP;
  for (int i=tid;i<n;i+=256) lv[i] = cval[b*CAP+i];
  __syncthreads();
  for (int r=0;r<64;++r){
    float best = -3.4e38f; int bi = -1;
    for (int i=tid;i<n;i+=256){
      float v = lv[i];
      if (v > best){ best = v; bi = i; }
    }
    sv[tid]=best; si[tid]=bi;
    __syncthreads();
    for (int st=128; st>0; st>>=1){
      if (tid < st && sv[tid+st] > sv[tid]){ sv[tid]=sv[tid+st]; si[tid]=si[tid+st]; }
      __syncthreads();
    }
    if (tid == 0){
      int kb = si[0];
      if (kb >= 0){
        tv[b*64+r] = sv[0];
        ti[b*64+r] = cidx[b*CAP+kb];
        lv[kb] = -3.4e38f;
      } else { tv[b*64+r] = 0.0f; ti[b*64+r] = 0; }
    }
    __syncthreads();
  }
}

// ============ K4a: fill decoder input with down_b ============
__global__ void k_fill(float* __restrict__ dst, const float* __restrict__ downb){
  const int bc = blockIdx.x;
  const int c = bc & 127;
  float v = downb[c];
  float4 vv; vv.x=v; vv.y=v; vv.z=v; vv.w=v;
  float4* p = (float4*)(dst + (size_t)bc*NT);
  for (int i=threadIdx.x; i < NT/4; i += 256) p[i] = vv;
}

// ============ K4b: scatter spikes through down_w ============
__global__ void k_scat(float* __restrict__ dst, const float* __restrict__ downw,
                       const float* __restrict__ tv, const int* __restrict__ ti){
  const int b = blockIdx.x, r = blockIdx.y;
  float v = tv[b*64+r];
  int idx = ti[b*64+r];
  int u = idx / NT, t = idx - u*NT;
  int c = threadIdx.x;
  atomicAdd(&dst[(size_t)(b*NC+c)*NT + t], downw[(size_t)c*NUP + u] * v);
}

// ============ K6: transposed filterbank synthesis (fp32, conflict-free) ============
#define TS 4096
__global__ __launch_bounds__(256) void k_syn(const float* __restrict__ dec,
                                             const float* __restrict__ fb,
                                             float* __restrict__ part){
  const int ts = blockIdx.x;    // 8
  const int cs = blockIdx.y;    // 32 (4 channels each)
  const int b  = blockIdx.z;
  const int t0 = ts * TS;
  __shared__ float win2[16*289 + 8];
  __shared__ float fbl[512];
  const int tid = threadIdx.x;
  const int tl = tid * 16;
  float acc[16];
  #pragma unroll
  for (int j=0;j<16;++j) acc[j] = 0.0f;
  for (int c = cs*4; c < cs*4+4; ++c){
    __syncthreads();
    for (int i=tid; i < TS+511; i += 256){
      int t = t0 - 255 + i;
      win2[(i & 15)*289 + (i >> 4)] = ((u32)t < (u32)NT) ? dec[(size_t)(b*NC+c)*NT + t] : 0.0f;
    }
    for (int i=tid; i<512; i+=256) fbl[i] = fb[c*KFB + i];
    __syncthreads();
    float w[23];
    #pragma unroll
    for (int k=0;k<23;++k){
      int i = tl + 504 + k;
      w[k] = win2[(i & 15)*289 + (i >> 4)];
    }
    for (int G=0; G<64; ++G){
      float4 f0 = *(const float4*)&fbl[G*8];
      float4 f1 = *(const float4*)&fbl[G*8+4];
      float fq[8] = {f0.x, f0.y, f0.z, f0.w, f1.x, f1.y, f1.z, f1.w};
      #pragma unroll
      for (int q=0;q<8;++q){
        #pragma unroll
        for (int jj=0;jj<16;++jj)
          acc[jj] = fmaf(fq[q], w[7-q+jj], acc[jj]);
      }
      if (G != 63){
        #pragma unroll
        for (int k=22;k>=8;--k) w[k] = w[k-8];
        #pragma unroll
        for (int k=0;k<8;++k){
          int i = tl + 496 - 8*G + k;
          w[k] = win2[(i & 15)*289 + (i >> 4)];
        }
      }
    }
  }
  float* po = &part[(size_t)(cs*NB + b)*NT + t0 + tl];
  #pragma unroll
  for (int m=0;m<4;++m){
    float4 ov; ov.x=acc[m*4+0]; ov.y=acc[m*4+1]; ov.z=acc[m*4+2]; ov.w=acc[m*4+3];
    *(float4*)&po[m*4] = ov;
  }
}

// ============ K6r: reduce partials -> out ============
__global__ void k_red(const float* __restrict__ part, float* __restrict__ out){
  int i = blockIdx.x*256 + threadIdx.x;
  float s = 0.0f;
  #pragma unroll
  for (int cs=0;cs<32;++cs) s += part[(size_t)cs*(NB*NT) + i];
  out[i] = s;
}

extern "C" void kernel_launch(void* const* d_in, const int* in_sizes, int n_in,
                              void* d_out, int out_size, void* d_ws, size_t ws_size,
                              hipStream_t stream){
  const float* x    = (const float*)d_in[0];
  const float* fb   = (const float*)d_in[1];
  const float* encw = (const float*)d_in[2];
  const float* encb = (const float*)d_in[3];
  const float* upw  = (const float*)d_in[4];
  const float* upb  = (const float*)d_in[5];
  const float* dnw  = (const float*)d_in[6];
  const float* dnb  = (const float*)d_in[7];
  const float* decw = (const float*)d_in[8];
  const float* decb = (const float*)d_in[9];
  float* out = (float*)d_out;
  char* ws = (char*)d_ws;

  size_t o = 0;
  float* bufA = (float*)(ws + o); o += (size_t)NB*NC*NT*4;
  float* bufB = (float*)(ws + o); o += (size_t)NB*NC*NT*4;
  u32*  keys  = (u32*)(ws + o);   o += (size_t)NB*NUP*1024*4;   // reused as `part`
  u32*  hist1 = (u32*)(ws + o);   o += 1024*NB*4;
  u32*  hist2 = (u32*)(ws + o);   o += 1024*NB*4;
  u32*  cstar = (u32*)(ws + o);   o += 64;
  u32*  nab   = (u32*)(ws + o);   o += 64;
  u32*  t0k   = (u32*)(ws + o);   o += 64;
  int*  cnt   = (int*)(ws + o);   o += 64;
  float* tv   = (float*)(ws + o); o += NB*64*4;
  int*  ti    = (int*)(ws + o);   o += NB*64*4;
  float* cval = (float*)(ws + o); o += (size_t)NB*CAP*4;
  int*  cidx  = (int*)(ws + o);   o += (size_t)NB*CAP*4;
  u16*  wdil  = (u16*)(ws + o);   o += (size_t)12*65536*2;
  u16*  wup   = (u16*)(ws + o);   o += (size_t)4*128*1024*2;
  u16*  wfb   = (u16*)(ws + o);   o += (size_t)128*1024*2;
  float* part = (float*)keys;     // keys dead after k_h2; 32*NB*NT*4 = 8.4 MB

  k_init<<<dim3(16), dim3(256), 0, stream>>>(hist1, hist2, cnt);
  k_prep<<<dim3(352), dim3(256), 0, stream>>>(encw, decw, upw, fb, wdil, wup, wfb);
  k_fb<<<dim3(256,NB), dim3(256), 0, stream>>>(x, wfb, bufA);

  // fused encoder stack: bufA -> bufB   (256 rows x 132 stride x 4B = 135168 B LDS)
  k_stack<<<dim3(256,NB), dim3(512), 256*RS*4, stream>>>(bufA, bufB, wdil, encb, 0);

  k_sub<<<dim3(32,4,NB), dim3(256), 0, stream>>>(bufB, upw, upb, keys, hist1);
  k_sel<<<dim3(NB), dim3(256), 0, stream>>>(hist1, cstar, nab, t0k, 1);
  k_h2 <<<dim3(4096), dim3(256), 0, stream>>>(keys, cstar, hist2);
  k_sel<<<dim3(NB), dim3(256), 0, stream>>>(hist2, cstar, nab, t0k, 2);
  k_up <<<dim3(256,NB), dim3(256), 128*RS*4, stream>>>(bufB, wup, upb, t0k, cval, cidx, cnt);
  k_top<<<dim3(NB), dim3(256), 0, stream>>>(cval, cidx, cnt, tv, ti);

  // decoder input: bufA = down_b + spikes
  k_fill<<<dim3(NB*NC), dim3(256), 0, stream>>>(bufA, dnb);
  k_scat<<<dim3(NB,64), dim3(128), 0, stream>>>(bufA, dnw, tv, ti);

  // fused decoder stack: bufA -> bufB
  k_stack<<<dim3(256,NB), dim3(512), 256*RS*4, stream>>>(bufA, bufB, wdil + (size_t)6*65536, decb, 1);

  k_syn<<<dim3(8,32,NB), dim3(256), 0, stream>>>(bufB, fb, part);
  k_red<<<dim3(256), dim3(256), 0, stream>>>(part, out);
}

// Round 6
// 819.468 us; speedup vs baseline: 3.0848x; 1.0549x over previous
//
#include <hip/hip_runtime.h>
#include <stdint.h>

#define NB  2
#define NC  128
#define NT  32768
#define KFB 512
#define NUP 2048
#define CAP 14336

typedef unsigned int u32;
typedef unsigned short u16;
typedef short s16;
typedef float f32x4 __attribute__((ext_vector_type(4)));
typedef s16 short8 __attribute__((ext_vector_type(8)));
typedef u32 u32x4 __attribute__((ext_vector_type(4)));

__device__ __forceinline__ u32 f2key(float v){
  u32 u = __float_as_uint(v);
  return (u & 0x80000000u) ? ~u : (u | 0x80000000u);
}
__device__ __forceinline__ float key2f(u32 k){
  u32 u = (k & 0x80000000u) ? (k & 0x7FFFFFFFu) : ~k;
  return __uint_as_float(u);
}
__device__ __forceinline__ u16 bf16rn(float v){
  u32 u = __float_as_uint(v);
  return (u16)((u + 0x7FFFu + ((u>>16)&1u)) >> 16);
}
__device__ __forceinline__ u32 packhl(float v){
  u16 h = bf16rn(v);
  u16 lo = bf16rn(v - __uint_as_float(((u32)h)<<16));
  return ((u32)h<<16) | lo;
}
__device__ __forceinline__ void unpack8(const u32* p, short8& xh, short8& xl){
  u32x4 r0 = *(const u32x4*)p;
  u32x4 r1 = *(const u32x4*)(p + 4);
  union { u32 u[4]; short8 v; } H, L;
  H.u[0] = __builtin_amdgcn_perm(r0.y, r0.x, 0x07060302u);
  H.u[1] = __builtin_amdgcn_perm(r0.w, r0.z, 0x07060302u);
  H.u[2] = __builtin_amdgcn_perm(r1.y, r1.x, 0x07060302u);
  H.u[3] = __builtin_amdgcn_perm(r1.w, r1.z, 0x07060302u);
  L.u[0] = __builtin_amdgcn_perm(r0.y, r0.x, 0x05040100u);
  L.u[1] = __builtin_amdgcn_perm(r0.w, r0.z, 0x05040100u);
  L.u[2] = __builtin_amdgcn_perm(r1.y, r1.x, 0x05040100u);
  L.u[3] = __builtin_amdgcn_perm(r1.w, r1.z, 0x05040100u);
  xh = H.v; xl = L.v;
}

// LDS row stride for [T][ci] tiles: 132 ≡ 4 (mod 32)
#define RS 132

// ============ K_prep: init + split weights to bf16 hi/lo in MFMA A-fragment order ============
__global__ __launch_bounds__(256) void k_prep(const float* __restrict__ encw,
    const float* __restrict__ decw, const float* __restrict__ upw,
    const float* __restrict__ fbw,
    u16* __restrict__ wdil, u16* __restrict__ wup, u16* __restrict__ wfb,
    u32* __restrict__ h1, u32* __restrict__ h2, int* __restrict__ counts){
  int g = blockIdx.x*256 + threadIdx.x;
  if (g < 2048) h1[g] = 0u;
  else if (g < 4096) h2[g-2048] = 0u;
  if (g < NB) counts[g] = 0;
  if (g < 49152){
    int l = g & 63, mt = (g>>6)&7, s = (g>>9)&7, layer = g>>12;
    const float* W = (layer < 6) ? (encw + (size_t)layer*NC*NC*2)
                                 : (decw + (size_t)(layer-6)*NC*NC*2);
    int co = mt*16 + (l & 15);
    int kb = s*32 + ((l>>4)<<3);
    union { u16 h[8]; u32x4 q; } H, L;
    #pragma unroll
    for (int j=0;j<8;++j){
      int k = kb + j;
      float v = W[((size_t)co*NC + (k&127))*2 + (k>>7)];
      u16 h = bf16rn(v);
      H.h[j] = h;
      L.h[j] = bf16rn(v - __uint_as_float(((u32)h)<<16));
    }
    int unit = g >> 6;
    *(u32x4*)(wdil + (size_t)unit*1024 + (l<<3)) = H.q;
    *(u32x4*)(wdil + (size_t)unit*1024 + 512 + (l<<3)) = L.q;
  } else if (g < 81920){
    int g2 = g - 49152;
    int l = g2 & 63, umt = (g2>>6)&127, s = g2>>13;
    int u = umt*16 + (l & 15);
    int kb = s*32 + ((l>>4)<<3);
    union { u16 h[8]; u32x4 q; } H, L;
    #pragma unroll
    for (int j=0;j<8;++j){
      float v = upw[(size_t)u*NC + kb + j];
      u16 h = bf16rn(v);
      H.h[j] = h;
      L.h[j] = bf16rn(v - __uint_as_float(((u32)h)<<16));
    }
    int unit = g2 >> 6;
    *(u32x4*)(wup + (size_t)unit*1024 + (l<<3)) = H.q;
    *(u32x4*)(wup + (size_t)unit*1024 + 512 + (l<<3)) = L.q;
  } else if (g < 90112){
    int g3 = g - 81920;
    int l = g3 & 63, mt = (g3>>6)&7, s = g3>>9;
    int c = mt*16 + (l & 15);
    int kb = s*32 + ((l>>4)<<3);
    union { u16 h[8]; u32x4 q; } H, L;
    #pragma unroll
    for (int j=0;j<8;++j){
      float v = fbw[(size_t)c*KFB + kb + j];
      u16 h = bf16rn(v);
      H.h[j] = h;
      L.h[j] = bf16rn(v - __uint_as_float(((u32)h)<<16));
    }
    int unit = g3 >> 6;
    *(u32x4*)(wfb + (size_t)unit*1024 + (l<<3)) = H.q;
    *(u32x4*)(wfb + (size_t)unit*1024 + 512 + (l<<3)) = L.q;
  }
}

// ============ K1: filterbank analysis — bf16x3 MFMA ============
__global__ __launch_bounds__(256) void k_fb(const float* __restrict__ x,
    const u16* __restrict__ wfb, float* __restrict__ spec){
  __shared__ u32 xw[640];
  const int tid = threadIdx.x;
  const int t0 = blockIdx.x << 7;
  const int b  = blockIdx.y;
  const int lane = tid & 63, w = tid >> 6;
  const int wy = w >> 1, wx = w & 1;
  const int quad = lane >> 4, l15 = lane & 15;
  for (int i = tid; i < 640; i += 256){
    int t = t0 - 256 + i;
    float v = ((u32)t < (u32)NT) ? x[b*NT + t] : 0.0f;
    xw[i] = packhl(v);
  }
  __syncthreads();
  f32x4 acc[4][4] = {};
  for (int s = 0; s < 16; ++s){
    short8 ah[4], al[4];
    #pragma unroll
    for (int mt=0; mt<4; ++mt){
      const u16* p = wfb + (size_t)(s*8 + wy*4 + mt)*1024 + (lane<<3);
      ah[mt] = *(const short8*)p;
      al[mt] = *(const short8*)(p + 512);
    }
    short8 xh[4], xl[4];
    #pragma unroll
    for (int nt=0; nt<4; ++nt){
      int base = s*32 + quad*8 + (wx<<6) + (nt<<4) + l15;
      u32 r[8];
      #pragma unroll
      for (int j=0;j<8;++j) r[j] = xw[base + j];
      union { u32 u[4]; short8 v; } H, L;
      H.u[0] = __builtin_amdgcn_perm(r[1], r[0], 0x07060302u);
      H.u[1] = __builtin_amdgcn_perm(r[3], r[2], 0x07060302u);
      H.u[2] = __builtin_amdgcn_perm(r[5], r[4], 0x07060302u);
      H.u[3] = __builtin_amdgcn_perm(r[7], r[6], 0x07060302u);
      L.u[0] = __builtin_amdgcn_perm(r[1], r[0], 0x05040100u);
      L.u[1] = __builtin_amdgcn_perm(r[3], r[2], 0x05040100u);
      L.u[2] = __builtin_amdgcn_perm(r[5], r[4], 0x05040100u);
      L.u[3] = __builtin_amdgcn_perm(r[7], r[6], 0x05040100u);
      xh[nt] = H.v; xl[nt] = L.v;
    }
    #pragma unroll
    for (int mt=0; mt<4; ++mt){
      #pragma unroll
      for (int nt=0; nt<4; ++nt){
        acc[mt][nt] = __builtin_amdgcn_mfma_f32_16x16x32_bf16(ah[mt], xh[nt], acc[mt][nt], 0,0,0);
        acc[mt][nt] = __builtin_amdgcn_mfma_f32_16x16x32_bf16(ah[mt], xl[nt], acc[mt][nt], 0,0,0);
        acc[mt][nt] = __builtin_amdgcn_mfma_f32_16x16x32_bf16(al[mt], xh[nt], acc[mt][nt], 0,0,0);
      }
    }
  }
  #pragma unroll
  for (int mt=0; mt<4; ++mt){
    #pragma unroll
    for (int r=0; r<4; ++r){
      const int c = (wy<<6) + (mt<<4) + (quad<<2) + r;
      float* po = spec + (size_t)(b*NC+c)*NT + t0 + (wx<<6) + l15;
      #pragma unroll
      for (int nt=0; nt<4; ++nt) po[nt<<4] = acc[mt][nt][r];
    }
  }
}

// ============ K2: fused 6-layer dilated stack — bf16x3 MFMA, 16 waves, halo-trimmed ============
// 1024 threads = 16 waves: wm 0..3 (32 co), wn 0..3 (64 t). Wave tile 32co x 64t.
// Per-layer active rows: enc [0, 128+H_l), dec [122-H_l, 250); trimmed rows hold
// stale-but-finite values that are provably never read by later layers.
__global__ __launch_bounds__(1024,4) void k_stack(const float* __restrict__ xin,
    float* __restrict__ xout, const u16* __restrict__ wf,
    const float* __restrict__ biases, int mode){
  extern __shared__ u32 lx[];           // [row 256][RS]
  const int tid = threadIdx.x;
  const int b  = blockIdx.y;
  const int T0 = blockIdx.x << 7;
  const int row0g = mode ? (T0 - 122) : T0;
  const int lane = tid & 63, w = tid >> 6;
  const int wm = w >> 2, wn = w & 3;
  const int quad = lane >> 4, l15 = lane & 15;
  // ---- stage-in: row = tid&255 (contiguous t per wave), 32 ci per thread
  {
    const float* xb = xin + (size_t)b*NC*NT;
    const int row = tid & 255;
    const int ci0 = (tid >> 8) << 5;
    const int tg = row0g + row;
    const bool ok = ((u32)tg < (u32)NT);
    const float* src = xb + (size_t)ci0*NT + tg;
    u32* dst = lx + row*RS + ci0;
    #pragma unroll
    for (int g=0; g<8; ++g){
      u32x4 q;
      #pragma unroll
      for (int k=0;k<4;++k){
        float v = ok ? src[(size_t)(g*4 + k)*NT] : 0.0f;
        q[k] = packhl(v);
      }
      *(u32x4*)(dst + g*4) = q;
    }
  }
  const int dils[6] = {1,3,9,27,81,1};
  const int Hrem[6] = {121,118,109,82,1,0};
  #pragma unroll 1
  for (int l = 0; l < 6; ++l){
    const int d = dils[l];
    const int o0 = mode ? -d : 0;
    const int o1 = mode ? 0 : d;
    const int lo = mode ? (122 - Hrem[l]) : 0;
    const int hi = mode ? 250 : (128 + Hrem[l]);
    const u16* wl = wf + ((size_t)l << 16);
    __syncthreads();
    bool act[4];
    #pragma unroll
    for (int nt=0;nt<4;++nt){
      const int Tst = (wn<<6) + (nt<<4);
      act[nt] = (Tst + 16 > lo) && (Tst < hi);
    }
    f32x4 acc[2][4] = {};
    #pragma unroll 1
    for (int s = 0; s < 8; ++s){
      short8 ah[2], al[2];
      #pragma unroll
      for (int mt=0;mt<2;++mt){
        const u16* p = wl + (size_t)(((s<<3) + (wm<<1) + mt) << 10) + (lane<<3);
        ah[mt] = *(const short8*)p;
        al[mt] = *(const short8*)(p + 512);
      }
      const int o = (s >= 4) ? o1 : o0;
      const int cig = (s & 3) << 5;
      #pragma unroll
      for (int nt=0;nt<4;++nt){
        if (!act[nt]) continue;
        const int T = ((wn<<6) + (nt<<4) + l15 + o) & 255;
        const int idx = T*RS + cig + (quad<<3);
        short8 xh, xl;
        unpack8(&lx[idx], xh, xl);
        #pragma unroll
        for (int mt=0;mt<2;++mt){
          acc[mt][nt] = __builtin_amdgcn_mfma_f32_16x16x32_bf16(ah[mt], xh, acc[mt][nt], 0,0,0);
          acc[mt][nt] = __builtin_amdgcn_mfma_f32_16x16x32_bf16(ah[mt], xl, acc[mt][nt], 0,0,0);
          acc[mt][nt] = __builtin_amdgcn_mfma_f32_16x16x32_bf16(al[mt], xh, acc[mt][nt], 0,0,0);
        }
      }
    }
    __syncthreads();
    // ---- epilogue: x = x + leaky(h + bias); zero outside [0,NT)
    const float* bl = biases + l*NC;
    const bool last = (l == 5);
    #pragma unroll
    for (int mt=0;mt<2;++mt){
      const int cobase = (wm<<5) + (mt<<4) + (quad<<2);
      float bv[4];
      #pragma unroll
      for (int r=0;r<4;++r) bv[r] = bl[cobase + r];
      #pragma unroll
      for (int nt=0;nt<4;++nt){
        if (!act[nt]) continue;
        const int T = (wn<<6) + (nt<<4) + l15;
        const int idx = T*RS + cobase;
        u32x4 xo = *(const u32x4*)&lx[idx];
        const int tg = row0g + T;
        const bool tvld = ((u32)tg < (u32)NT);
        float nv[4];
        #pragma unroll
        for (int r=0;r<4;++r){
          float oldv = __uint_as_float(xo[r] & 0xFFFF0000u) + __uint_as_float(xo[r] << 16);
          float h = acc[mt][nt][r] + bv[r];
          h = (h >= 0.f) ? h : 0.2f*h;
          float xn = oldv + h;
          nv[r] = tvld ? xn : 0.0f;
        }
        if (!last){
          u32x4 np;
          #pragma unroll
          for (int r=0;r<4;++r) np[r] = packhl(nv[r]);
          *(u32x4*)&lx[idx] = np;
        } else {
          const bool rowok = mode ? (T >= 122 && T < 250) : (T < 128);
          if (rowok){
            float* po = xout + (size_t)(b*NC + cobase)*NT + tg;
            #pragma unroll
            for (int r=0;r<4;++r) po[(size_t)r*NT] = nv[r];
          }
        }
      }
    }
  }
}

// ============ K3a: up-proj on t-subsample (fp32, keys + coarse hist) ============
__global__ __launch_bounds__(256) void k_sub(const float* __restrict__ enc,
                                             const float* __restrict__ upw,
                                             const float* __restrict__ upb,
                                             u32* __restrict__ keys,
                                             u32* __restrict__ hist1){
  const int u0 = blockIdx.x * 64;
  const int i0 = blockIdx.y * 256;
  const int b  = blockIdx.z;
  __shared__ float uwl[32][68];
  __shared__ float ec[32][260];
  __shared__ u32 lh[1024];
  const int tid = threadIdx.x;
  for (int i=tid;i<1024;i+=256) lh[i] = 0u;
  const int ug = tid & 15;
  const int ig = tid >> 4;
  float acc[4][16];
  #pragma unroll
  for (int i=0;i<4;++i){
    #pragma unroll
    for (int j=0;j<16;++j) acc[i][j]=0.0f;
  }
  for (int c0=0;c0<NC;c0+=32){
    __syncthreads();
    #pragma unroll
    for (int i=0;i<8;++i){
      int flat = i*256+tid;
      uwl[flat & 31][flat >> 5] = upw[(size_t)(u0 + (flat>>5))*NC + c0 + (flat&31)];
    }
    #pragma unroll
    for (int i=0;i<32;++i){
      int flat = i*256+tid;
      ec[flat >> 8][flat & 255] = enc[(size_t)(b*NC + c0 + (flat>>8))*NT + (size_t)(i0 + (flat&255))*32];
    }
    __syncthreads();
    #pragma unroll 2
    for (int cc=0;cc<32;++cc){
      float a[4], bb[16];
      *(float4*)&a[0] = *(const float4*)&uwl[cc][ug*4];
      #pragma unroll
      for (int m=0;m<4;++m)
        *(float4*)&bb[m*4] = *(const float4*)&ec[cc][ig*16 + m*4];
      #pragma unroll
      for (int i=0;i<4;++i){
        #pragma unroll
        for (int j=0;j<16;++j)
          acc[i][j] = fmaf(a[i], bb[j], acc[i][j]);
      }
    }
  }
  #pragma unroll
  for (int i=0;i<4;++i){
    int u = u0 + ug*4 + i;
    float ub = upb[u];
    #pragma unroll
    for (int j=0;j<16;++j){
      float v = acc[i][j] + ub;
      u32 k = f2key(v);
      keys[(size_t)(b*NUP + u)*1024 + i0 + ig*16 + j] = k;
      atomicAdd(&lh[k >> 22], 1u);
    }
  }
  __syncthreads();
  for (int i=tid;i<1024;i+=256){
    u32 c = lh[i];
    if (c) atomicAdd(&hist1[b*1024 + i], c);
  }
}

// ============ K3sel: suffix-scan histogram, pick rank-64 bin ============
__global__ __launch_bounds__(256) void k_sel(const u32* __restrict__ hist,
                                             u32* __restrict__ cstar,
                                             u32* __restrict__ nab,
                                             u32* __restrict__ t0key,
                                             int phase){
  const int b = blockIdx.x;
  __shared__ u32 s1[1024];
  __shared__ u32 s2[1024];
  __shared__ int red[256];
  const int tid = threadIdx.x;
  for (int i=tid;i<1024;i+=256) s1[i] = hist[b*1024 + i];
  __syncthreads();
  u32* cur = s1; u32* nxt = s2;
  for (int off=1; off<1024; off<<=1){
    for (int i=tid;i<1024;i+=256){
      u32 v = cur[i];
      if (i + off < 1024) v += cur[i+off];
      nxt[i] = v;
    }
    __syncthreads();
    u32* t = cur; cur = nxt; nxt = t;
  }
  u32 off0 = (phase==1) ? 0u : nab[b];
  int best = -1;
  for (int i=tid;i<1024;i+=256)
    if (off0 + cur[i] >= 64u && i > best) best = i;
  red[tid] = best;
  __syncthreads();
  for (int st=128; st>0; st>>=1){
    if (tid < st) red[tid] = max(red[tid], red[tid+st]);
    __syncthreads();
  }
  if (tid == 0){
    int bi = (red[0] < 0) ? 0 : red[0];
    if (phase == 1){
      cstar[b] = (u32)bi;
      nab[b] = (bi < 1023) ? cur[bi+1] : 0u;
    } else {
      t0key[b] = (cstar[b] << 22) | (((u32)bi) << 12);
    }
  }
}

// ============ K3h2: fine histogram within coarse bin ============
__global__ void k_h2(const u32* __restrict__ keys, const u32* __restrict__ cstar,
                     u32* __restrict__ hist2){
  const u32 c0 = cstar[0], c1 = cstar[1];
  int i = blockIdx.x*256 + threadIdx.x;
  const int total = NB*NUP*1024;
  const int stride = gridDim.x*256;
  for (; i < total; i += stride){
    u32 k = keys[i];
    u32 cs = (i >> 21) ? c1 : c0;
    if ((k >> 22) == cs) atomicAdd(&hist2[((u32)(i>>21)<<10) + ((k>>12) & 1023u)], 1u);
  }
}

// ============ K3b: full up-proj — bf16x3 MFMA, t-tile resident, u-chunk loop ============
__global__ __launch_bounds__(256,2) void k_up(const float* __restrict__ enc,
    const u16* __restrict__ wf, const float* __restrict__ upb,
    const u32* __restrict__ t0key, float* __restrict__ cval,
    int* __restrict__ cidx, int* __restrict__ counts){
  extern __shared__ u32 lx[];   // [128][RS]
  const int tid = threadIdx.x;
  const int t0 = blockIdx.x << 7;
  const int b  = blockIdx.y;
  const int lane = tid & 63, w = tid >> 6;
  const int wy = w >> 1, wx = w & 1;
  const int quad = lane >> 4, l15 = lane & 15;
  {
    const float* xb = enc + (size_t)b*NC*NT + t0;
    const int row = tid >> 1;
    const int ci0 = (tid & 1) << 6;
    const float* src = xb + (size_t)ci0*NT + row;
    u32* dst = lx + row*RS + ci0;
    #pragma unroll
    for (int g=0; g<16; ++g){
      u32x4 q;
      #pragma unroll
      for (int k=0;k<4;++k) q[k] = packhl(src[(size_t)(g*4 + k)*NT]);
      *(u32x4*)(dst + g*4) = q;
    }
  }
  __syncthreads();
  float T0 = key2f(t0key[b]);
  T0 -= fabsf(T0)*3e-4f + 1e-5f;
  #pragma unroll 1
  for (int uc = 0; uc < 16; ++uc){
    f32x4 acc[4][4] = {};
    #pragma unroll 1
    for (int s = 0; s < 4; ++s){
      short8 ah[4], al[4];
      #pragma unroll
      for (int mt=0;mt<4;++mt){
        const u16* p = wf + (size_t)((s*128 + uc*8 + wy*4 + mt) << 10) + (lane<<3);
        ah[mt] = *(const short8*)p;
        al[mt] = *(const short8*)(p + 512);
      }
      const int cig = s << 5;
      #pragma unroll
      for (int nt=0;nt<4;++nt){
        const int T = (wx<<6) + (nt<<4) + l15;
        short8 xh, xl;
        unpack8(&lx[T*RS + cig + (quad<<3)], xh, xl);
        #pragma unroll
        for (int mt=0;mt<4;++mt){
          acc[mt][nt] = __builtin_amdgcn_mfma_f32_16x16x32_bf16(ah[mt], xh, acc[mt][nt], 0,0,0);
          acc[mt][nt] = __builtin_amdgcn_mfma_f32_16x16x32_bf16(ah[mt], xl, acc[mt][nt], 0,0,0);
          acc[mt][nt] = __builtin_amdgcn_mfma_f32_16x16x32_bf16(al[mt], xh, acc[mt][nt], 0,0,0);
        }
      }
    }
    #pragma unroll
    for (int mt=0; mt<4; ++mt){
      #pragma unroll
      for (int r=0; r<4; ++r){
        int u = uc*128 + (wy<<6) + (mt<<4) + (quad<<2) + r;
        float ub = upb[u];
        #pragma unroll
        for (int nt=0; nt<4; ++nt){
          float v = acc[mt][nt][r] + ub;
          if (v >= T0){
            int slot = atomicAdd(&counts[b], 1);
            if (slot < CAP){
              cval[b*CAP + slot] = v;
              cidx[b*CAP + slot] = u*NT + (t0 + (wx<<6) + (nt<<4) + l15);
            }
          }
        }
      }
    }
  }
}

// ============ K3c: exact top-64 — register-cached fast path ============
__global__ __launch_bounds__(256) void k_top(const float* __restrict__ cval,
                                             const int* __restrict__ cidx,
                                             const int* __restrict__ counts,
                                             float* __restrict__ tv,
                                             int* __restrict__ ti){
  const int b = blockIdx.x;
  __shared__ float lv[CAP];
  __shared__ float sv[256];
  __shared__ int   si[256];
  const int tid = threadIdx.x;
  int n = counts[b]; if (n > CAP) n = CAP;
  if (n <= 4096){
    float v[16];
    #pragma unroll
    for (int r=0;r<16;++r){
      int i = r*256 + tid;
      v[r] = (i < n) ? cval[b*CAP+i] : -3.4e38f;
    }
    const int lane = tid & 63, wv = tid >> 6;
    for (int r=0;r<64;++r){
      float best = v[0]; int bidx = 0;
      #pragma unroll
      for (int k=1;k<16;++k){ if (v[k] > best){ best = v[k]; bidx = k; } }
      int gi = bidx*256 + tid;
      #pragma unroll
      for (int off=32; off>0; off>>=1){
        float ov = __shfl_down(best, off);
        int oi = __shfl_down(gi, off);
        if (ov > best){ best = ov; gi = oi; }
      }
      if (lane == 0){ sv[wv] = best; si[wv] = gi; }
      __syncthreads();
      if (tid == 0){
        float bb = sv[0]; int bbi = si[0];
        #pragma unroll
        for (int k=1;k<4;++k) if (sv[k] > bb){ bb = sv[k]; bbi = si[k]; }
        si[4] = bbi;
        if (bb > -3.0e38f){ tv[b*64+r] = bb; ti[b*64+r] = cidx[b*CAP + bbi]; }
        else { tv[b*64+r] = 0.0f; ti[b*64+r] = 0; }
      }
      __syncthreads();
      int wini = si[4];
      if ((wini & 255) == tid) v[wini >> 8] = -3.4e38f;
    }
  } else {
    for (int i=tid;i<n;i+=256) lv[i] = cval[b*CAP+i];
    __syncthreads();
    for (int r=0;r<64;++r){
      float best = -3.4e38f; int bi = -1;
      for (int i=tid;i<n;i+=256){
        float v = lv[i];
        if (v > best){ best = v; bi = i; }
      }
      sv[tid]=best; si[tid]=bi;
      __syncthreads();
      for (int st=128; st>0; st>>=1){
        if (tid < st && sv[tid+st] > sv[tid]){ sv[tid]=sv[tid+st]; si[tid]=si[tid+st]; }
        __syncthreads();
      }
      if (tid == 0){
        int kb = si[0];
        if (kb >= 0){
          tv[b*64+r] = sv[0];
          ti[b*64+r] = cidx[b*CAP+kb];
          lv[kb] = -3.4e38f;
        } else { tv[b*64+r] = 0.0f; ti[b*64+r] = 0; }
      }
      __syncthreads();
    }
  }
}

// ============ K4a: fill decoder input with down_b ============
__global__ void k_fill(float* __restrict__ dst, const float* __restrict__ downb){
  const int bc = blockIdx.x;
  const int c = bc & 127;
  float v = downb[c];
  float4 vv; vv.x=v; vv.y=v; vv.z=v; vv.w=v;
  float4* p = (float4*)(dst + (size_t)bc*NT);
  for (int i=threadIdx.x; i < NT/4; i += 256) p[i] = vv;
}

// ============ K4b: scatter spikes through down_w ============
__global__ void k_scat(float* __restrict__ dst, const float* __restrict__ downw,
                       const float* __restrict__ tv, const int* __restrict__ ti){
  const int b = blockIdx.x, r = blockIdx.y;
  float v = tv[b*64+r];
  int idx = ti[b*64+r];
  int u = idx / NT, t = idx - u*NT;
  int c = threadIdx.x;
  atomicAdd(&dst[(size_t)(b*NC+c)*NT + t], downw[(size_t)c*NUP + u] * v);
}

// ============ K6: transposed filterbank synthesis (fp32, 2 ch/block, 4 blocks/CU) ============
#define TS 4096
__global__ __launch_bounds__(256) void k_syn(const float* __restrict__ dec,
                                             const float* __restrict__ fb,
                                             float* __restrict__ part){
  const int ts = blockIdx.x;    // 8
  const int cs = blockIdx.y;    // 64 (2 channels each)
  const int b  = blockIdx.z;
  const int t0 = ts * TS;
  __shared__ float win2[16*289 + 8];
  __shared__ float fbl[512];
  const int tid = threadIdx.x;
  const int tl = tid * 16;
  float acc[16];
  #pragma unroll
  for (int j=0;j<16;++j) acc[j] = 0.0f;
  for (int c = cs*2; c < cs*2+2; ++c){
    __syncthreads();
    for (int i=tid; i < TS+511; i += 256){
      int t = t0 - 255 + i;
      win2[(i & 15)*289 + (i >> 4)] = ((u32)t < (u32)NT) ? dec[(size_t)(b*NC+c)*NT + t] : 0.0f;
    }
    for (int i=tid; i<512; i+=256) fbl[i] = fb[c*KFB + i];
    __syncthreads();
    float w[23];
    #pragma unroll
    for (int k=0;k<23;++k){
      int i = tl + 504 + k;
      w[k] = win2[(i & 15)*289 + (i >> 4)];
    }
    for (int G=0; G<64; ++G){
      float4 f0 = *(const float4*)&fbl[G*8];
      float4 f1 = *(const float4*)&fbl[G*8+4];
      float fq[8] = {f0.x, f0.y, f0.z, f0.w, f1.x, f1.y, f1.z, f1.w};
      #pragma unroll
      for (int q=0;q<8;++q){
        #pragma unroll
        for (int jj=0;jj<16;++jj)
          acc[jj] = fmaf(fq[q], w[7-q+jj], acc[jj]);
      }
      if (G != 63){
        #pragma unroll
        for (int k=22;k>=8;--k) w[k] = w[k-8];
        #pragma unroll
        for (int k=0;k<8;++k){
          int i = tl + 496 - 8*G + k;
          w[k] = win2[(i & 15)*289 + (i >> 4)];
        }
      }
    }
  }
  float* po = &part[(size_t)(cs*NB + b)*NT + t0 + tl];
  #pragma unroll
  for (int m=0;m<4;++m){
    float4 ov; ov.x=acc[m*4+0]; ov.y=acc[m*4+1]; ov.z=acc[m*4+2]; ov.w=acc[m*4+3];
    *(float4*)&po[m*4] = ov;
  }
}

// ============ K6r: reduce partials -> out ============
__global__ void k_red(const float* __restrict__ part, float* __restrict__ out){
  int i = blockIdx.x*256 + threadIdx.x;
  float s = 0.0f;
  #pragma unroll
  for (int cs=0;cs<64;++cs) s += part[(size_t)cs*(NB*NT) + i];
  out[i] = s;
}

extern "C" void kernel_launch(void* const* d_in, const int* in_sizes, int n_in,
                              void* d_out, int out_size, void* d_ws, size_t ws_size,
                              hipStream_t stream){
  const float* x    = (const float*)d_in[0];
  const float* fb   = (const float*)d_in[1];
  const float* encw = (const float*)d_in[2];
  const float* encb = (const float*)d_in[3];
  const float* upw  = (const float*)d_in[4];
  const float* upb  = (const float*)d_in[5];
  const float* dnw  = (const float*)d_in[6];
  const float* dnb  = (const float*)d_in[7];
  const float* decw = (const float*)d_in[8];
  const float* decb = (const float*)d_in[9];
  float* out = (float*)d_out;
  char* ws = (char*)d_ws;

  size_t o = 0;
  float* bufA = (float*)(ws + o); o += (size_t)NB*NC*NT*4;
  float* bufB = (float*)(ws + o); o += (size_t)NB*NC*NT*4;
  u32*  keys  = (u32*)(ws + o);   o += (size_t)NB*NUP*1024*4;   // reused as `part`
  u32*  hist1 = (u32*)(ws + o);   o += 1024*NB*4;
  u32*  hist2 = (u32*)(ws + o);   o += 1024*NB*4;
  u32*  cstar = (u32*)(ws + o);   o += 64;
  u32*  nab   = (u32*)(ws + o);   o += 64;
  u32*  t0k   = (u32*)(ws + o);   o += 64;
  int*  cnt   = (int*)(ws + o);   o += 64;
  float* tv   = (float*)(ws + o); o += NB*64*4;
  int*  ti    = (int*)(ws + o);   o += NB*64*4;
  float* cval = (float*)(ws + o); o += (size_t)NB*CAP*4;
  int*  cidx  = (int*)(ws + o);   o += (size_t)NB*CAP*4;
  u16*  wdil  = (u16*)(ws + o);   o += (size_t)12*65536*2;
  u16*  wup   = (u16*)(ws + o);   o += (size_t)4*128*1024*2;
  u16*  wfb   = (u16*)(ws + o);   o += (size_t)128*1024*2;
  float* part = (float*)keys;     // keys dead after k_h2; 64*NB*NT*4 = 16.78 MB fits

  k_prep<<<dim3(352), dim3(256), 0, stream>>>(encw, decw, upw, fb, wdil, wup, wfb, hist1, hist2, cnt);
  k_fb<<<dim3(256,NB), dim3(256), 0, stream>>>(x, wfb, bufA);

  // fused encoder stack: bufA -> bufB
  k_stack<<<dim3(256,NB), dim3(1024), 256*RS*4, stream>>>(bufA, bufB, wdil, encb, 0);

  k_sub<<<dim3(32,4,NB), dim3(256), 0, stream>>>(bufB, upw, upb, keys, hist1);
  k_sel<<<dim3(NB), dim3(256), 0, stream>>>(hist1, cstar, nab, t0k, 1);
  k_h2 <<<dim3(4096), dim3(256), 0, stream>>>(keys, cstar, hist2);
  k_sel<<<dim3(NB), dim3(256), 0, stream>>>(hist2, cstar, nab, t0k, 2);
  k_up <<<dim3(256,NB), dim3(256), 128*RS*4, stream>>>(bufB, wup, upb, t0k, cval, cidx, cnt);
  k_top<<<dim3(NB), dim3(256), 0, stream>>>(cval, cidx, cnt, tv, ti);

  // decoder input: bufA = down_b + spikes
  k_fill<<<dim3(NB*NC), dim3(256), 0, stream>>>(bufA, dnb);
  k_scat<<<dim3(NB,64), dim3(128), 0, stream>>>(bufA, dnw, tv, ti);

  // fused decoder stack: bufA -> bufB
  k_stack<<<dim3(256,NB), dim3(1024), 256*RS*4, stream>>>(bufA, bufB, wdil + (size_t)6*65536, decb, 1);

  k_syn<<<dim3(8,64,NB), dim3(256), 0, stream>>>(bufB, fb, part);
  k_red<<<dim3(256), dim3(256), 0, stream>>>(part, out);
}